// Round 3
// baseline (47492.090 us; speedup 1.0000x reference)
//
#include <hip/hip_runtime.h>
#include <hip/hip_bf16.h>
#include <math.h>

typedef __hip_bfloat16 bf16;

#define BB 16
#define SS 512
#define EE 512
#define HH 8
#define DH 64
#define LL 3
#define MM (BB*SS)          // 8192 tokens
#define OBSD 128
#define ACTD 17
#define INV_SQRT_D 0.125f

#define ACT_NONE 0
#define ACT_GELU 1

#define NORM_PLAIN 0
#define NORM_ADD 1
#define NORM_SWIGLU 2

__device__ __forceinline__ float gelu_f(float x){
  float x3 = x*x*x;
  return 0.5f*x*(1.f + tanhf(0.7978845608028654f*(x + 0.044715f*x3)));
}
__device__ __forceinline__ float silu_f(float x){ return x/(1.f+expf(-x)); }
__device__ __forceinline__ float lkappa(int h){ return logf(1.f - exp2f(-5.f - (float)h)); }

// ---------------- GEMM: C[M,512] = act(scale*((A+A2)@W) + bias), all fp32 ----------------
__global__ __launch_bounds__(256) void gemm_kernel(
    const float* __restrict__ A, const float* __restrict__ A2,
    const float* __restrict__ W, const float* __restrict__ bias,
    float* __restrict__ C, int K, int N, float scale, int act)
{
  __shared__ float As[16][68];
  __shared__ float Bs[16][68];
  const int bm = blockIdx.y*64, bn = blockIdx.x*64;
  const int tid = threadIdx.x;
  const int tx = tid & 15, ty = tid >> 4;
  float acc[4][4];
  #pragma unroll
  for (int i=0;i<4;i++){
    #pragma unroll
    for (int j=0;j<4;j++) acc[i][j]=0.f;
  }
  for (int k0=0;k0<K;k0+=16){
    #pragma unroll
    for (int it=0; it<4; ++it){
      int i = tid + it*256;
      int m = i>>4, kk = i&15; int gk = k0+kk;
      float a = 0.f;
      if (gk < K){
        size_t off = (size_t)(bm+m)*K + gk;
        a = A[off];
        if (A2) a += A2[off];
      }
      As[kk][m] = a;
    }
    #pragma unroll
    for (int it=0; it<4; ++it){
      int i = tid + it*256;
      int n = i&63, kk = i>>6; int gk = k0+kk;
      Bs[kk][n] = (gk<K) ? W[(size_t)gk*N + bn + n] : 0.f;
    }
    __syncthreads();
    #pragma unroll
    for (int kk=0;kk<16;kk++){
      float4 a4 = *(const float4*)&As[kk][ty*4];
      float4 b4 = *(const float4*)&Bs[kk][tx*4];
      float av[4] = {a4.x,a4.y,a4.z,a4.w};
      float bv[4] = {b4.x,b4.y,b4.z,b4.w};
      #pragma unroll
      for (int i=0;i<4;i++){
        #pragma unroll
        for (int j=0;j<4;j++) acc[i][j] += av[i]*bv[j];
      }
    }
    __syncthreads();
  }
  #pragma unroll
  for (int i=0;i<4;i++){
    int row = bm + ty*4 + i;
    #pragma unroll
    for (int j=0;j<4;j++){
      int col = bn + tx*4 + j;
      float v = acc[i][j]*scale;
      if (bias) v += bias[col];
      if (act==ACT_GELU) v = gelu_f(v);
      C[(size_t)row*N + col] = v;
    }
  }
}

// ---------------- fused rmsnorm family (fp32 in/out) ----------------
__global__ __launch_bounds__(256) void norm_kernel(
    const float* __restrict__ a, const float* __restrict__ b,
    const float* __restrict__ g, const float* __restrict__ p,
    const float* __restrict__ w, float* __restrict__ outp,
    int cols, int mode)
{
  __shared__ float rowbuf[EE];
  __shared__ float red[4];
  const int row = blockIdx.x, tid = threadIdx.x;
  float ss = 0.f;
  for (int c = tid; c < cols; c += 256){
    size_t off = (size_t)row*cols + c;
    float t = a[off];
    if (mode == NORM_ADD) t += b[off];
    else if (mode == NORM_SWIGLU) t += silu_f(g[off])*p[off];
    rowbuf[c] = t;
    ss += t*t;
  }
  #pragma unroll
  for (int o=32;o;o>>=1) ss += __shfl_down(ss,o);
  if ((tid&63)==0) red[tid>>6]=ss;
  __syncthreads();
  if (tid==0){
    float s = red[0]+red[1]+red[2]+red[3];
    red[0] = 1.f/sqrtf(s/(float)cols + 1e-6f);
  }
  __syncthreads();
  float r = red[0];
  for (int c = tid; c < cols; c += 256)
    outp[(size_t)row*cols + c] = rowbuf[c]*r*w[c];
}

// ---------------- retention core: out = dmat*(qk^T) @ v + (q@h0)*xi ----------------
__global__ __launch_bounds__(256) void retention_kernel(
    const float* __restrict__ q, const float* __restrict__ k, const float* __restrict__ v,
    const float* __restrict__ h0, const int* __restrict__ tsi,
    float* __restrict__ outp, int masked)
{
  __shared__ float ksh[64*68];      // k chunk [m][d] pitch 68 (also h0^T [e][d] in prologue)
  __shared__ float vts[64*68];      // v chunk transposed [e][m] pitch 68
  __shared__ float qsh[4][32][64];  // per-wave q rows
  __shared__ float csh[4][8][64];   // per-wave coefficients
  __shared__ float tsf[SS];
  const int b = blockIdx.z, h = blockIdx.y;
  const int n0 = blockIdx.x * 128;
  const int tid = threadIdx.x, lane = tid & 63, wv = tid >> 6;
  const float lk = lkappa(h);
  for (int i = tid; i < SS; i += 256) tsf[i] = (float)tsi[b*SS + i];
  const float* h0b = h0 + (size_t)b*(LL*HH*DH*DH) + (size_t)h*(DH*DH);
  for (int i = tid; i < DH*DH; i += 256){
    int d = i >> 6, e = i & 63;
    ksh[e*68 + d] = h0b[i];    // transposed
  }
  __syncthreads();
  const int rowbase = n0 + wv*32;
  const size_t qbase = ((size_t)b*SS + rowbase)*EE + h*DH;
  for (int rr = 0; rr < 32; ++rr)
    qsh[wv][rr][lane] = q[qbase + (size_t)rr*EE + lane];
  float acc[32];
  #pragma unroll
  for (int rr = 0; rr < 32; ++rr){
    const float* qr = qsh[wv][rr];
    const float* hr = &ksh[lane*68];
    float s0=0.f,s1=0.f,s2=0.f,s3=0.f;
    #pragma unroll
    for (int d = 0; d < 64; d += 4){
      float4 q4 = *(const float4*)&qr[d];
      float4 h4 = *(const float4*)&hr[d];
      s0 += q4.x*h4.x; s1 += q4.y*h4.y; s2 += q4.z*h4.z; s3 += q4.w*h4.w;
    }
    float tsn = tsf[rowbase+rr];
    acc[rr] = (s0+s1+s2+s3)*expf(lk*(tsn+1.f));
  }
  __syncthreads();
  for (int mc = 0; mc < SS; mc += 64){
    #pragma unroll
    for (int it = 0; it < 4; ++it){
      int i = tid + it*256;
      int m = i >> 4, c = i & 15;
      size_t goff = ((size_t)b*SS + mc + m)*EE + h*DH + c*4;
      float4 k4 = *(const float4*)&k[goff];
      *(float4*)&ksh[m*68 + c*4] = k4;
      float4 v4 = *(const float4*)&v[goff];
      vts[(c*4+0)*68 + m] = v4.x;
      vts[(c*4+1)*68 + m] = v4.y;
      vts[(c*4+2)*68 + m] = v4.z;
      vts[(c*4+3)*68 + m] = v4.w;
    }
    __syncthreads();
    const float tsm = tsf[mc + lane];
    const int mg = mc + lane;
    #pragma unroll
    for (int g = 0; g < 4; ++g){
      const int r0 = g*8;
      float cf[8];
      #pragma unroll
      for (int r=0;r<8;r++) cf[r]=0.f;
      const float* kr = &ksh[lane*68];
      #pragma unroll
      for (int d = 0; d < 64; d += 4){
        float4 k4 = *(const float4*)&kr[d];
        #pragma unroll
        for (int r = 0; r < 8; ++r){
          float4 q4 = *(const float4*)&qsh[wv][r0+r][d];
          cf[r] += k4.x*q4.x + k4.y*q4.y + k4.z*q4.z + k4.w*q4.w;
        }
      }
      #pragma unroll
      for (int r = 0; r < 8; ++r){
        int n = rowbase + r0 + r;
        float diff = tsf[n] - tsm;
        float wgt;
        if (masked){
          wgt = ((diff > 0.f) || (diff == 0.f && n >= mg)) ? expf(lk*diff) : 0.f;
        } else {
          wgt = expf(lk*fabsf(diff));
        }
        csh[wv][r][lane] = cf[r]*wgt;
      }
      const float* vr = &vts[lane*68];
      #pragma unroll
      for (int m4 = 0; m4 < 64; m4 += 4){
        float4 vv = *(const float4*)&vr[m4];
        #pragma unroll
        for (int r = 0; r < 8; ++r){
          float4 c4 = *(const float4*)&csh[wv][r][m4];
          acc[r0+r] += vv.x*c4.x + vv.y*c4.y + vv.z*c4.z + vv.w*c4.w;
        }
      }
    }
    __syncthreads();
  }
  const size_t obase = ((size_t)b*SS + rowbase)*EE + h*DH;
  #pragma unroll
  for (int rr = 0; rr < 32; ++rr)
    outp[obase + (size_t)rr*EE + lane] = acc[rr];
}

// ---------------- recurrent state: partial outer-product over m quarters ----------------
__global__ __launch_bounds__(256) void hstate_partial_kernel(
    const float* __restrict__ k, const float* __restrict__ v,
    const int* __restrict__ tsi, const float* __restrict__ tmx,
    float* __restrict__ part)
{
  __shared__ float ksh[64*68];
  __shared__ float vsh[64*64];
  __shared__ float wsh[64];
  const int qr = blockIdx.x, h = blockIdx.y, b = blockIdx.z;
  const int tid = threadIdx.x, lane = tid & 63, wv = tid >> 6;
  const float lk = lkappa(h);
  const float tm = tmx[b];
  float acc[16];
  #pragma unroll
  for (int i=0;i<16;i++) acc[i]=0.f;
  for (int mc = qr*128; mc < qr*128 + 128; mc += 64){
    #pragma unroll
    for (int it=0; it<4; ++it){
      int i = tid + it*256;
      int m = i>>4, c = i&15;
      size_t goff = ((size_t)b*SS + mc + m)*EE + h*DH + c*4;
      *(float4*)&ksh[m*68 + c*4] = *(const float4*)&k[goff];
      *(float4*)&vsh[m*64 + c*4] = *(const float4*)&v[goff];
    }
    if (tid < 64) wsh[tid] = expf(lk*(tm - (float)tsi[b*SS + mc + tid]));
    __syncthreads();
    for (int m = 0; m < 64; ++m){
      float wvv = wsh[m]*vsh[m*64 + lane];
      const float* kr = &ksh[m*68 + wv*16];
      #pragma unroll
      for (int i = 0; i < 16; i += 4){
        float4 k4 = *(const float4*)&kr[i];
        acc[i+0] += k4.x*wvv; acc[i+1] += k4.y*wvv;
        acc[i+2] += k4.z*wvv; acc[i+3] += k4.w*wvv;
      }
    }
    __syncthreads();
  }
  float* pp = part + ((((size_t)b*HH + h)*4 + qr)*DH + wv*16)*DH + lane;
  #pragma unroll
  for (int i=0;i<16;i++) pp[(size_t)i*DH] = acc[i];
}

__global__ __launch_bounds__(256) void hstate_final_kernel(
    const float* __restrict__ part, const float* __restrict__ h0,
    const float* __restrict__ tmx, float* __restrict__ outp)
{
  int idx = blockIdx.x*256 + threadIdx.x;  // B*H*64*64 = 524288
  int e = idx & 63, d = (idx>>6) & 63, h = (idx>>12) & 7, b = idx >> 15;
  float lk = lkappa(h);
  float dec = expf(lk*(tmx[b] + 1.f));
  const float* pp = part + (((size_t)b*HH + h)*4*DH + d)*DH + e;
  float s = pp[0] + pp[DH*DH] + pp[2*DH*DH] + pp[3*DH*DH];
  size_t off = (size_t)b*(LL*HH*DH*DH) + (size_t)h*DH*DH + d*DH + e;
  outp[off] = dec*h0[off] + s;
}

// ---------------- small helpers ----------------
__global__ void tsmax_kernel(const int* __restrict__ tsi, float* __restrict__ tmx){
  __shared__ int red[4];
  int b = blockIdx.x, tid = threadIdx.x;
  int m = max(tsi[b*SS+tid], tsi[b*SS+256+tid]);
  #pragma unroll
  for (int o=32;o;o>>=1) m = max(m, __shfl_down(m,o));
  if ((tid&63)==0) red[tid>>6]=m;
  __syncthreads();
  if (tid==0) tmx[b] = (float)max(max(red[0],red[1]),max(red[2],red[3]));
}

__global__ void pe_kernel(const int* __restrict__ tsi, float* __restrict__ pe){
  int idx = blockIdx.x*256 + threadIdx.x;   // MM*EE total
  int row = idx >> 9, j = idx & 511;
  float ts = (float)tsi[row];
  int jj = j & 255;
  float freq = expf(-9.210340371976184f*(float)jj*(1.f/256.f));
  float ang = ts*freq;
  pe[idx] = (j < 256) ? sinf(ang) : cosf(ang);
}

__global__ __launch_bounds__(256) void head_kernel(
    const float* __restrict__ x, const float* __restrict__ w,
    const float* __restrict__ bias, float* __restrict__ outp, int N)
{
  const int row = blockIdx.x*4 + (threadIdx.x>>6);
  const int lane = threadIdx.x & 63;
  const float* xr = x + (size_t)row*EE;
  float xv[8];
  #pragma unroll
  for (int i=0;i<8;i++) xv[i] = xr[lane + 64*i];
  for (int j=0;j<N;j++){
    float s = 0.f;
    #pragma unroll
    for (int i=0;i<8;i++) s += xv[i]*w[(size_t)(lane+64*i)*N + j];
    #pragma unroll
    for (int o=32;o;o>>=1) s += __shfl_down(s,o);
    if (lane==0) outp[(size_t)row*N + j] = s + bias[j];
  }
}

// ---------------- orchestration ----------------
extern "C" void kernel_launch(void* const* d_in, const int* in_sizes, int n_in,
                              void* d_out, int out_size, void* d_ws, size_t ws_size,
                              hipStream_t stream)
{
  const float* obs     = (const float*)d_in[0];
  const float* action  = (const float*)d_in[1];
  const float* enc_hs  = (const float*)d_in[2];
  const float* dec_hs1 = (const float*)d_in[3];
  const float* dec_hs2 = (const float*)d_in[4];
  const int*   stepc   = (const int*)d_in[5];
  const float* eoln = (const float*)d_in[6];
  const float* eow  = (const float*)d_in[7];
  const float* eln  = (const float*)d_in[8];
  const float* ewq  = (const float*)d_in[9];
  const float* ewk  = (const float*)d_in[10];
  const float* ewv  = (const float*)d_in[11];
  const float* ewo  = (const float*)d_in[12];
  const float* eln1 = (const float*)d_in[13];
  const float* eln2 = (const float*)d_in[14];
  const float* efg  = (const float*)d_in[15];
  const float* efp  = (const float*)d_in[16];
  const float* ehw1 = (const float*)d_in[17];
  const float* ehb1 = (const float*)d_in[18];
  const float* ehln = (const float*)d_in[19];
  const float* ehw2 = (const float*)d_in[20];
  const float* ehb2 = (const float*)d_in[21];
  const float* daw  = (const float*)d_in[22];
  const float* dln  = (const float*)d_in[23];
  const float* dwq1 = (const float*)d_in[24];
  const float* dwk1 = (const float*)d_in[25];
  const float* dwv1 = (const float*)d_in[26];
  const float* dwo1 = (const float*)d_in[27];
  const float* dwq2 = (const float*)d_in[28];
  const float* dwk2 = (const float*)d_in[29];
  const float* dwv2 = (const float*)d_in[30];
  const float* dwo2 = (const float*)d_in[31];
  const float* dln1 = (const float*)d_in[32];
  const float* dln2 = (const float*)d_in[33];
  const float* dln3 = (const float*)d_in[34];
  const float* dfg  = (const float*)d_in[35];
  const float* dfp  = (const float*)d_in[36];
  const float* dhw1 = (const float*)d_in[37];
  const float* dhb1 = (const float*)d_in[38];
  const float* dhln = (const float*)d_in[39];
  const float* dhw2 = (const float*)d_in[40];
  const float* dhb2 = (const float*)d_in[41];

  const size_t BUF = (size_t)MM*EE;          // 4194304 floats
  const size_t PART = (size_t)BB*HH*4*DH*DH; // 2097152 floats
  if (ws_size < (9*BUF + PART + 64)*sizeof(float)) return;

  float* wsf  = (float*)d_ws;
  float* pe   = wsf;
  float* xrep = pe   + BUF;
  float* x    = xrep + BUF;
  float* xn   = x    + BUF;
  float* qb   = xn   + BUF;
  float* kb   = qb   + BUF;
  float* vb   = kb   + BUF;
  float* rp   = vb   + BUF;
  float* t1   = rp   + BUF;
  float* part = t1   + BUF;
  float* tmx  = part + PART;

  float* out        = (float*)d_out;
  float* value_out  = out;
  float* logits_out = out + 8192;
  float* enc_out    = logits_out + (size_t)MM*16;
  float* d1_out     = enc_out + (size_t)BB*LL*HH*DH*DH;
  float* d2_out     = d1_out  + (size_t)BB*LL*HH*DH*DH;

  const size_t WMAT = (size_t)EE*EE;
  const size_t HS_L = (size_t)HH*DH*DH;

  auto gemm = [&](const float* A, const float* A2, const float* W, const float* bias,
                  float* C, int K, float scale, int act){
    gemm_kernel<<<dim3(EE/64, MM/64), 256, 0, stream>>>(A, A2, W, bias, C, K, EE, scale, act);
  };
  auto norm = [&](const float* a, const float* b2, const float* g, const float* p,
                  const float* w, float* o, int cols, int mode){
    norm_kernel<<<MM, 256, 0, stream>>>(a, b2, g, p, w, o, cols, mode);
  };

  // ---- prologue: positional encoding + per-batch timestep max ----
  pe_kernel<<<(MM*EE)/256, 256, 0, stream>>>(stepc, pe);
  tsmax_kernel<<<BB, 256, 0, stream>>>(stepc, tmx);

  // ---- encoder embed: obs_rep = gelu(rmsnorm(obs, eoln) @ eow) ----
  norm(obs, nullptr, nullptr, nullptr, eoln, t1, OBSD, NORM_PLAIN);
  gemm(t1, nullptr, eow, nullptr, xrep, OBSD, 1.f, ACT_GELU);

  // ---- encoder layers ----
  for (int i = 0; i < LL; ++i){
    norm(xrep, nullptr, nullptr, nullptr, eln, xn, EE, NORM_PLAIN);
    gemm(xn, pe, ewq + i*WMAT, nullptr, qb, EE, 1.f, ACT_NONE);
    gemm(xn, pe, ewk + i*WMAT, nullptr, kb, EE, INV_SQRT_D, ACT_NONE);
    gemm(xn, pe, ewv + i*WMAT, nullptr, vb, EE, 1.f, ACT_NONE);
    retention_kernel<<<dim3(4,HH,BB), 256, 0, stream>>>(qb, kb, vb, enc_hs + i*HS_L, stepc, rp, 0);
    hstate_partial_kernel<<<dim3(4,HH,BB), 256, 0, stream>>>(kb, vb, stepc, tmx, part);
    hstate_final_kernel<<<2048, 256, 0, stream>>>(part, enc_hs + i*HS_L, tmx, enc_out + i*HS_L);
    gemm(rp, nullptr, ewo + i*WMAT, nullptr, vb, EE, 1.f, ACT_NONE);
    norm(xn, vb, nullptr, nullptr, eln1 + i*EE, t1, EE, NORM_ADD);
    gemm(t1, nullptr, efg + i*WMAT, nullptr, qb, EE, 1.f, ACT_NONE);
    gemm(t1, nullptr, efp + i*WMAT, nullptr, kb, EE, 1.f, ACT_NONE);
    norm(t1, nullptr, qb, kb, eln2 + i*EE, xrep, EE, NORM_SWIGLU);
  }

  // ---- value head ----
  gemm(xrep, nullptr, ehw1, ehb1, t1, EE, 1.f, ACT_GELU);
  norm(t1, nullptr, nullptr, nullptr, ehln, qb, EE, NORM_PLAIN);
  head_kernel<<<MM/4, 256, 0, stream>>>(qb, ehw2, ehb2, value_out, 1);

  // ---- decoder embed: x = rmsnorm(gelu(action @ daw), dln) ----
  gemm(action, nullptr, daw, nullptr, qb, ACTD, 1.f, ACT_GELU);
  norm(qb, nullptr, nullptr, nullptr, dln, x, EE, NORM_PLAIN);

  // ---- decoder layers ----
  for (int i = 0; i < LL; ++i){
    // self retention (masked)
    gemm(x, pe, dwq1 + i*WMAT, nullptr, qb, EE, 1.f, ACT_NONE);
    gemm(x, pe, dwk1 + i*WMAT, nullptr, kb, EE, INV_SQRT_D, ACT_NONE);
    gemm(x, pe, dwv1 + i*WMAT, nullptr, vb, EE, 1.f, ACT_NONE);
    retention_kernel<<<dim3(4,HH,BB), 256, 0, stream>>>(qb, kb, vb, dec_hs1 + i*HS_L, stepc, rp, 1);
    hstate_partial_kernel<<<dim3(4,HH,BB), 256, 0, stream>>>(kb, vb, stepc, tmx, part);
    hstate_final_kernel<<<2048, 256, 0, stream>>>(part, dec_hs1 + i*HS_L, tmx, d1_out + i*HS_L);
    gemm(rp, nullptr, dwo1 + i*WMAT, nullptr, vb, EE, 1.f, ACT_NONE);
    norm(x, vb, nullptr, nullptr, dln1 + i*EE, t1, EE, NORM_ADD);      // r
    // cross retention (masked): q from obs_rep, k/v from r
    gemm(xrep, pe, dwq2 + i*WMAT, nullptr, qb, EE, 1.f, ACT_NONE);
    gemm(t1,   pe, dwk2 + i*WMAT, nullptr, kb, EE, INV_SQRT_D, ACT_NONE);
    gemm(t1,   pe, dwv2 + i*WMAT, nullptr, vb, EE, 1.f, ACT_NONE);
    retention_kernel<<<dim3(4,HH,BB), 256, 0, stream>>>(qb, kb, vb, dec_hs2 + i*HS_L, stepc, rp, 1);
    hstate_partial_kernel<<<dim3(4,HH,BB), 256, 0, stream>>>(kb, vb, stepc, tmx, part);
    hstate_final_kernel<<<2048, 256, 0, stream>>>(part, dec_hs2 + i*HS_L, tmx, d2_out + i*HS_L);
    gemm(rp, nullptr, dwo2 + i*WMAT, nullptr, vb, EE, 1.f, ACT_NONE);
    norm(xrep, vb, nullptr, nullptr, dln2 + i*EE, x, EE, NORM_ADD);    // y
    // FFN
    gemm(x, nullptr, dfg + i*WMAT, nullptr, qb, EE, 1.f, ACT_NONE);
    gemm(x, nullptr, dfp + i*WMAT, nullptr, kb, EE, 1.f, ACT_NONE);
    norm(x, nullptr, qb, kb, dln3 + i*EE, x, EE, NORM_SWIGLU);
  }

  // ---- logits head ----
  gemm(x, nullptr, dhw1, dhb1, t1, EE, 1.f, ACT_GELU);
  norm(t1, nullptr, nullptr, nullptr, dhln, qb, EE, NORM_PLAIN);
  head_kernel<<<MM/4, 256, 0, stream>>>(qb, dhw2, dhb2, logits_out, 16);
}

// Round 4
// 9406.840 us; speedup vs baseline: 5.0487x; 5.0487x over previous
//
#include <hip/hip_runtime.h>
#include <hip/hip_bf16.h>
#include <math.h>

typedef __hip_bfloat16 bf16;

#define BB 16
#define SS 512
#define EE 512
#define HH 8
#define DH 64
#define LL 3
#define MM (BB*SS)          // 8192 tokens
#define OBSD 128
#define ACTD 17
#define INV_SQRT_D 0.125f

#define ACT_NONE 0
#define ACT_GELU 1

#define NORM_PLAIN 0
#define NORM_ADD 1
#define NORM_SWIGLU 2

__device__ __forceinline__ float gelu_f(float x){
  float x3 = x*x*x;
  return 0.5f*x*(1.f + tanhf(0.7978845608028654f*(x + 0.044715f*x3)));
}
__device__ __forceinline__ float silu_f(float x){ return x/(1.f+expf(-x)); }
__device__ __forceinline__ float lkappa(int h){ return logf(1.f - exp2f(-5.f - (float)h)); }

// ---------------- GEMM: C[M,512] = act(scale*((A+A2)@W) + bias), all fp32 ----------------
__global__ __launch_bounds__(256) void gemm_kernel(
    const float* __restrict__ A, const float* __restrict__ A2,
    const float* __restrict__ W, const float* __restrict__ bias,
    float* __restrict__ C, int K, int N, float scale, int act)
{
  __shared__ float As[16][68];
  __shared__ float Bs[16][68];
  const int bm = blockIdx.y*64, bn = blockIdx.x*64;
  const int tid = threadIdx.x;
  const int tx = tid & 15, ty = tid >> 4;
  float acc[4][4];
  #pragma unroll
  for (int i=0;i<4;i++){
    #pragma unroll
    for (int j=0;j<4;j++) acc[i][j]=0.f;
  }
  for (int k0=0;k0<K;k0+=16){
    #pragma unroll
    for (int it=0; it<4; ++it){
      int i = tid + it*256;
      int m = i>>4, kk = i&15; int gk = k0+kk;
      float a = 0.f;
      if (gk < K){
        size_t off = (size_t)(bm+m)*K + gk;
        a = A[off];
        if (A2) a += A2[off];
      }
      As[kk][m] = a;
    }
    #pragma unroll
    for (int it=0; it<4; ++it){
      int i = tid + it*256;
      int n = i&63, kk = i>>6; int gk = k0+kk;
      Bs[kk][n] = (gk<K) ? W[(size_t)gk*N + bn + n] : 0.f;
    }
    __syncthreads();
    #pragma unroll
    for (int kk=0;kk<16;kk++){
      float4 a4 = *(const float4*)&As[kk][ty*4];
      float4 b4 = *(const float4*)&Bs[kk][tx*4];
      float av[4] = {a4.x,a4.y,a4.z,a4.w};
      float bv[4] = {b4.x,b4.y,b4.z,b4.w};
      #pragma unroll
      for (int i=0;i<4;i++){
        #pragma unroll
        for (int j=0;j<4;j++) acc[i][j] += av[i]*bv[j];
      }
    }
    __syncthreads();
  }
  #pragma unroll
  for (int i=0;i<4;i++){
    int row = bm + ty*4 + i;
    #pragma unroll
    for (int j=0;j<4;j++){
      int col = bn + tx*4 + j;
      float v = acc[i][j]*scale;
      if (bias) v += bias[col];
      if (act==ACT_GELU) v = gelu_f(v);
      C[(size_t)row*N + col] = v;
    }
  }
}

// ---------------- fused rmsnorm family (fp32 in/out) ----------------
__global__ __launch_bounds__(256) void norm_kernel(
    const float* __restrict__ a, const float* __restrict__ b,
    const float* __restrict__ g, const float* __restrict__ p,
    const float* __restrict__ w, float* __restrict__ outp,
    int cols, int mode)
{
  __shared__ float rowbuf[EE];
  __shared__ float red[4];
  const int row = blockIdx.x, tid = threadIdx.x;
  float ss = 0.f;
  for (int c = tid; c < cols; c += 256){
    size_t off = (size_t)row*cols + c;
    float t = a[off];
    if (mode == NORM_ADD) t += b[off];
    else if (mode == NORM_SWIGLU) t += silu_f(g[off])*p[off];
    rowbuf[c] = t;
    ss += t*t;
  }
  #pragma unroll
  for (int o=32;o;o>>=1) ss += __shfl_down(ss,o);
  if ((tid&63)==0) red[tid>>6]=ss;
  __syncthreads();
  if (tid==0){
    float s = red[0]+red[1]+red[2]+red[3];
    red[0] = 1.f/sqrtf(s/(float)cols + 1e-6f);
  }
  __syncthreads();
  float r = red[0];
  for (int c = tid; c < cols; c += 256)
    outp[(size_t)row*cols + c] = rowbuf[c]*r*w[c];
}

// ---------------- retention core: out = dmat*(qk^T) @ v + (q@h0)*xi ----------------
// Spill-free rewrite: 16 rows/wave, 64 rows/block, pitch-65 LDS (conflict-free).
__global__ __launch_bounds__(256) void retention_kernel(
    const float* __restrict__ q, const float* __restrict__ k, const float* __restrict__ v,
    const float* __restrict__ h0, const int* __restrict__ tsi,
    float* __restrict__ outp, int masked)
{
  __shared__ float ksh[64*65];      // k chunk [m][d] pitch 65 (h0^T [e][d] in prologue)
  __shared__ float vsh[64*65];      // v chunk [m][e] pitch 65
  __shared__ float qsh[4][16][64];  // per-wave q rows
  __shared__ float csh[4][16][64];  // per-wave decayed coefficients
  __shared__ float tsf[SS];
  const int b = blockIdx.z, h = blockIdx.y;
  const int n0 = blockIdx.x * 64;
  const int tid = threadIdx.x, lane = tid & 63, wv = tid >> 6;
  const float lk = lkappa(h);
  for (int i = tid; i < SS; i += 256) tsf[i] = (float)tsi[b*SS + i];
  const float* h0b = h0 + (size_t)b*(LL*HH*DH*DH) + (size_t)h*(DH*DH);
  for (int i = tid; i < DH*DH; i += 256){
    int d = i >> 6, e = i & 63;
    ksh[e*65 + d] = h0b[i];        // transposed, pitch 65
  }
  const int rowbase = n0 + wv*16;
  const size_t qbase = ((size_t)b*SS + rowbase)*EE + h*DH;
  #pragma unroll
  for (int r = 0; r < 16; ++r)
    qsh[wv][r][lane] = q[qbase + (size_t)r*EE + lane];
  __syncthreads();
  // accumulator init: (q @ h0)[:, lane] * exp(lk*(ts+1))
  float acc[16];
  #pragma unroll
  for (int r = 0; r < 16; ++r){
    const float* qr = qsh[wv][r];
    const float* hr = &ksh[lane*65];
    float s = 0.f;
    #pragma unroll
    for (int d = 0; d < 64; d += 4){
      float4 q4 = *(const float4*)&qr[d];
      float4 h4 = *(const float4*)&hr[d];
      s += q4.x*h4.x + q4.y*h4.y + q4.z*h4.z + q4.w*h4.w;
    }
    acc[r] = s * expf(lk*(tsf[rowbase+r]+1.f));
  }
  __syncthreads();   // everyone done with h0^T before k overwrites ksh
  for (int mc = 0; mc < SS; mc += 64){
    #pragma unroll
    for (int it = 0; it < 4; ++it){
      int i = tid + it*256;
      int m = i >> 4, c = (i & 15)*4;
      size_t goff = ((size_t)b*SS + mc + m)*EE + h*DH + c;
      *(float4*)&ksh[m*65 + c] = *(const float4*)&k[goff];
      *(float4*)&vsh[m*65 + c] = *(const float4*)&v[goff];
    }
    __syncthreads();
    // score phase: lane = m
    const int mg = mc + lane;
    const float tsm = tsf[mg];
    float cf[16];
    #pragma unroll
    for (int r=0;r<16;r++) cf[r]=0.f;
    const float* kr = &ksh[lane*65];
    #pragma unroll 4
    for (int d = 0; d < 64; d += 4){
      float4 k4 = *(const float4*)&kr[d];
      #pragma unroll
      for (int r = 0; r < 16; ++r){
        float4 q4 = *(const float4*)&qsh[wv][r][d];
        cf[r] += k4.x*q4.x + k4.y*q4.y + k4.z*q4.z + k4.w*q4.w;
      }
    }
    #pragma unroll
    for (int r = 0; r < 16; ++r){
      int n = rowbase + r;
      float diff = tsf[n] - tsm;
      float wgt;
      if (masked) wgt = ((diff > 0.f) || (diff == 0.f && n >= mg)) ? expf(lk*diff) : 0.f;
      else        wgt = expf(lk*fabsf(diff));
      csh[wv][r][lane] = cf[r]*wgt;   // per-wave buffer, wave-coherent
    }
    // output phase: lane = e
    #pragma unroll 4
    for (int m4 = 0; m4 < 64; m4 += 4){
      float v0 = vsh[(m4+0)*65 + lane];
      float v1 = vsh[(m4+1)*65 + lane];
      float v2 = vsh[(m4+2)*65 + lane];
      float v3 = vsh[(m4+3)*65 + lane];
      #pragma unroll
      for (int r = 0; r < 16; ++r){
        float4 c4 = *(const float4*)&csh[wv][r][m4];
        acc[r] += c4.x*v0 + c4.y*v1 + c4.z*v2 + c4.w*v3;
      }
    }
    __syncthreads();
  }
  const size_t obase = ((size_t)b*SS + rowbase)*EE + h*DH;
  #pragma unroll
  for (int r = 0; r < 16; ++r)
    outp[obase + (size_t)r*EE + lane] = acc[r];
}

// ---------------- recurrent state: partial outer-product over m quarters ----------------
__global__ __launch_bounds__(256) void hstate_partial_kernel(
    const float* __restrict__ k, const float* __restrict__ v,
    const int* __restrict__ tsi, const float* __restrict__ tmx,
    float* __restrict__ part)
{
  __shared__ float ksh[64*68];
  __shared__ float vsh[64*64];
  __shared__ float wsh[64];
  const int qr = blockIdx.x, h = blockIdx.y, b = blockIdx.z;
  const int tid = threadIdx.x, lane = tid & 63, wv = tid >> 6;
  const float lk = lkappa(h);
  const float tm = tmx[b];
  float acc[16];
  #pragma unroll
  for (int i=0;i<16;i++) acc[i]=0.f;
  for (int mc = qr*128; mc < qr*128 + 128; mc += 64){
    #pragma unroll
    for (int it=0; it<4; ++it){
      int i = tid + it*256;
      int m = i>>4, c = i&15;
      size_t goff = ((size_t)b*SS + mc + m)*EE + h*DH + c*4;
      *(float4*)&ksh[m*68 + c*4] = *(const float4*)&k[goff];
      *(float4*)&vsh[m*64 + c*4] = *(const float4*)&v[goff];
    }
    if (tid < 64) wsh[tid] = expf(lk*(tm - (float)tsi[b*SS + mc + tid]));
    __syncthreads();
    for (int m = 0; m < 64; ++m){
      float wvv = wsh[m]*vsh[m*64 + lane];
      const float* kr = &ksh[m*68 + wv*16];
      #pragma unroll
      for (int i = 0; i < 16; i += 4){
        float4 k4 = *(const float4*)&kr[i];
        acc[i+0] += k4.x*wvv; acc[i+1] += k4.y*wvv;
        acc[i+2] += k4.z*wvv; acc[i+3] += k4.w*wvv;
      }
    }
    __syncthreads();
  }
  float* pp = part + ((((size_t)b*HH + h)*4 + qr)*DH + wv*16)*DH + lane;
  #pragma unroll
  for (int i=0;i<16;i++) pp[(size_t)i*DH] = acc[i];
}

__global__ __launch_bounds__(256) void hstate_final_kernel(
    const float* __restrict__ part, const float* __restrict__ h0,
    const float* __restrict__ tmx, float* __restrict__ outp)
{
  int idx = blockIdx.x*256 + threadIdx.x;  // B*H*64*64 = 524288
  int e = idx & 63, d = (idx>>6) & 63, h = (idx>>12) & 7, b = idx >> 15;
  float lk = lkappa(h);
  float dec = expf(lk*(tmx[b] + 1.f));
  const float* pp = part + (((size_t)b*HH + h)*4*DH + d)*DH + e;
  float s = pp[0] + pp[DH*DH] + pp[2*DH*DH] + pp[3*DH*DH];
  size_t off = (size_t)b*(LL*HH*DH*DH) + (size_t)h*DH*DH + d*DH + e;
  outp[off] = dec*h0[off] + s;
}

// ---------------- small helpers ----------------
__global__ void tsmax_kernel(const int* __restrict__ tsi, float* __restrict__ tmx){
  __shared__ int red[4];
  int b = blockIdx.x, tid = threadIdx.x;
  int m = max(tsi[b*SS+tid], tsi[b*SS+256+tid]);
  #pragma unroll
  for (int o=32;o;o>>=1) m = max(m, __shfl_down(m,o));
  if ((tid&63)==0) red[tid>>6]=m;
  __syncthreads();
  if (tid==0) tmx[b] = (float)max(max(red[0],red[1]),max(red[2],red[3]));
}

__global__ void pe_kernel(const int* __restrict__ tsi, float* __restrict__ pe){
  int idx = blockIdx.x*256 + threadIdx.x;   // MM*EE total
  int row = idx >> 9, j = idx & 511;
  float ts = (float)tsi[row];
  int jj = j & 255;
  float freq = expf(-9.210340371976184f*(float)jj*(1.f/256.f));
  float ang = ts*freq;
  pe[idx] = (j < 256) ? sinf(ang) : cosf(ang);
}

__global__ __launch_bounds__(256) void head_kernel(
    const float* __restrict__ x, const float* __restrict__ w,
    const float* __restrict__ bias, float* __restrict__ outp, int N)
{
  const int row = blockIdx.x*4 + (threadIdx.x>>6);
  const int lane = threadIdx.x & 63;
  const float* xr = x + (size_t)row*EE;
  float xv[8];
  #pragma unroll
  for (int i=0;i<8;i++) xv[i] = xr[lane + 64*i];
  for (int j=0;j<N;j++){
    float s = 0.f;
    #pragma unroll
    for (int i=0;i<8;i++) s += xv[i]*w[(size_t)(lane+64*i)*N + j];
    #pragma unroll
    for (int o=32;o;o>>=1) s += __shfl_down(s,o);
    if (lane==0) outp[(size_t)row*N + j] = s + bias[j];
  }
}

// ---------------- orchestration ----------------
extern "C" void kernel_launch(void* const* d_in, const int* in_sizes, int n_in,
                              void* d_out, int out_size, void* d_ws, size_t ws_size,
                              hipStream_t stream)
{
  const float* obs     = (const float*)d_in[0];
  const float* action  = (const float*)d_in[1];
  const float* enc_hs  = (const float*)d_in[2];
  const float* dec_hs1 = (const float*)d_in[3];
  const float* dec_hs2 = (const float*)d_in[4];
  const int*   stepc   = (const int*)d_in[5];
  const float* eoln = (const float*)d_in[6];
  const float* eow  = (const float*)d_in[7];
  const float* eln  = (const float*)d_in[8];
  const float* ewq  = (const float*)d_in[9];
  const float* ewk  = (const float*)d_in[10];
  const float* ewv  = (const float*)d_in[11];
  const float* ewo  = (const float*)d_in[12];
  const float* eln1 = (const float*)d_in[13];
  const float* eln2 = (const float*)d_in[14];
  const float* efg  = (const float*)d_in[15];
  const float* efp  = (const float*)d_in[16];
  const float* ehw1 = (const float*)d_in[17];
  const float* ehb1 = (const float*)d_in[18];
  const float* ehln = (const float*)d_in[19];
  const float* ehw2 = (const float*)d_in[20];
  const float* ehb2 = (const float*)d_in[21];
  const float* daw  = (const float*)d_in[22];
  const float* dln  = (const float*)d_in[23];
  const float* dwq1 = (const float*)d_in[24];
  const float* dwk1 = (const float*)d_in[25];
  const float* dwv1 = (const float*)d_in[26];
  const float* dwo1 = (const float*)d_in[27];
  const float* dwq2 = (const float*)d_in[28];
  const float* dwk2 = (const float*)d_in[29];
  const float* dwv2 = (const float*)d_in[30];
  const float* dwo2 = (const float*)d_in[31];
  const float* dln1 = (const float*)d_in[32];
  const float* dln2 = (const float*)d_in[33];
  const float* dln3 = (const float*)d_in[34];
  const float* dfg  = (const float*)d_in[35];
  const float* dfp  = (const float*)d_in[36];
  const float* dhw1 = (const float*)d_in[37];
  const float* dhb1 = (const float*)d_in[38];
  const float* dhln = (const float*)d_in[39];
  const float* dhw2 = (const float*)d_in[40];
  const float* dhb2 = (const float*)d_in[41];

  const size_t BUF = (size_t)MM*EE;          // 4194304 floats
  const size_t PART = (size_t)BB*HH*4*DH*DH; // 2097152 floats
  if (ws_size < (9*BUF + PART + 64)*sizeof(float)) return;

  float* wsf  = (float*)d_ws;
  float* pe   = wsf;
  float* xrep = pe   + BUF;
  float* x    = xrep + BUF;
  float* xn   = x    + BUF;
  float* qb   = xn   + BUF;
  float* kb   = qb   + BUF;
  float* vb   = kb   + BUF;
  float* rp   = vb   + BUF;
  float* t1   = rp   + BUF;
  float* part = t1   + BUF;
  float* tmx  = part + PART;

  float* out        = (float*)d_out;
  float* value_out  = out;
  float* logits_out = out + 8192;
  float* enc_out    = logits_out + (size_t)MM*16;
  float* d1_out     = enc_out + (size_t)BB*LL*HH*DH*DH;
  float* d2_out     = d1_out  + (size_t)BB*LL*HH*DH*DH;

  const size_t WMAT = (size_t)EE*EE;
  const size_t HS_L = (size_t)HH*DH*DH;

  auto gemm = [&](const float* A, const float* A2, const float* W, const float* bias,
                  float* C, int K, float scale, int act){
    gemm_kernel<<<dim3(EE/64, MM/64), 256, 0, stream>>>(A, A2, W, bias, C, K, EE, scale, act);
  };
  auto norm = [&](const float* a, const float* b2, const float* g, const float* p,
                  const float* w, float* o, int cols, int mode){
    norm_kernel<<<MM, 256, 0, stream>>>(a, b2, g, p, w, o, cols, mode);
  };
  auto retention = [&](const float* qp, const float* kp, const float* vp,
                       const float* h0, float* o, int masked){
    retention_kernel<<<dim3(8, HH, BB), 256, 0, stream>>>(qp, kp, vp, h0, stepc, o, masked);
  };

  // ---- prologue: positional encoding + per-batch timestep max ----
  pe_kernel<<<(MM*EE)/256, 256, 0, stream>>>(stepc, pe);
  tsmax_kernel<<<BB, 256, 0, stream>>>(stepc, tmx);

  // ---- encoder embed: obs_rep = gelu(rmsnorm(obs, eoln) @ eow) ----
  norm(obs, nullptr, nullptr, nullptr, eoln, t1, OBSD, NORM_PLAIN);
  gemm(t1, nullptr, eow, nullptr, xrep, OBSD, 1.f, ACT_GELU);

  // ---- encoder layers ----
  for (int i = 0; i < LL; ++i){
    norm(xrep, nullptr, nullptr, nullptr, eln, xn, EE, NORM_PLAIN);
    gemm(xn, pe, ewq + i*WMAT, nullptr, qb, EE, 1.f, ACT_NONE);
    gemm(xn, pe, ewk + i*WMAT, nullptr, kb, EE, INV_SQRT_D, ACT_NONE);
    gemm(xn, pe, ewv + i*WMAT, nullptr, vb, EE, 1.f, ACT_NONE);
    retention(qb, kb, vb, enc_hs + i*HS_L, rp, 0);
    hstate_partial_kernel<<<dim3(4,HH,BB), 256, 0, stream>>>(kb, vb, stepc, tmx, part);
    hstate_final_kernel<<<2048, 256, 0, stream>>>(part, enc_hs + i*HS_L, tmx, enc_out + i*HS_L);
    gemm(rp, nullptr, ewo + i*WMAT, nullptr, vb, EE, 1.f, ACT_NONE);
    norm(xn, vb, nullptr, nullptr, eln1 + i*EE, t1, EE, NORM_ADD);
    gemm(t1, nullptr, efg + i*WMAT, nullptr, qb, EE, 1.f, ACT_NONE);
    gemm(t1, nullptr, efp + i*WMAT, nullptr, kb, EE, 1.f, ACT_NONE);
    norm(t1, nullptr, qb, kb, eln2 + i*EE, xrep, EE, NORM_SWIGLU);
  }

  // ---- value head ----
  gemm(xrep, nullptr, ehw1, ehb1, t1, EE, 1.f, ACT_GELU);
  norm(t1, nullptr, nullptr, nullptr, ehln, qb, EE, NORM_PLAIN);
  head_kernel<<<MM/4, 256, 0, stream>>>(qb, ehw2, ehb2, value_out, 1);

  // ---- decoder embed: x = rmsnorm(gelu(action @ daw), dln) ----
  gemm(action, nullptr, daw, nullptr, qb, ACTD, 1.f, ACT_GELU);
  norm(qb, nullptr, nullptr, nullptr, dln, x, EE, NORM_PLAIN);

  // ---- decoder layers ----
  for (int i = 0; i < LL; ++i){
    // self retention (masked)
    gemm(x, pe, dwq1 + i*WMAT, nullptr, qb, EE, 1.f, ACT_NONE);
    gemm(x, pe, dwk1 + i*WMAT, nullptr, kb, EE, INV_SQRT_D, ACT_NONE);
    gemm(x, pe, dwv1 + i*WMAT, nullptr, vb, EE, 1.f, ACT_NONE);
    retention(qb, kb, vb, dec_hs1 + i*HS_L, rp, 1);
    hstate_partial_kernel<<<dim3(4,HH,BB), 256, 0, stream>>>(kb, vb, stepc, tmx, part);
    hstate_final_kernel<<<2048, 256, 0, stream>>>(part, dec_hs1 + i*HS_L, tmx, d1_out + i*HS_L);
    gemm(rp, nullptr, dwo1 + i*WMAT, nullptr, vb, EE, 1.f, ACT_NONE);
    norm(x, vb, nullptr, nullptr, dln1 + i*EE, t1, EE, NORM_ADD);      // r
    // cross retention (masked): q from obs_rep, k/v from r
    gemm(xrep, pe, dwq2 + i*WMAT, nullptr, qb, EE, 1.f, ACT_NONE);
    gemm(t1,   pe, dwk2 + i*WMAT, nullptr, kb, EE, INV_SQRT_D, ACT_NONE);
    gemm(t1,   pe, dwv2 + i*WMAT, nullptr, vb, EE, 1.f, ACT_NONE);
    retention(qb, kb, vb, dec_hs2 + i*HS_L, rp, 1);
    hstate_partial_kernel<<<dim3(4,HH,BB), 256, 0, stream>>>(kb, vb, stepc, tmx, part);
    hstate_final_kernel<<<2048, 256, 0, stream>>>(part, dec_hs2 + i*HS_L, tmx, d2_out + i*HS_L);
    gemm(rp, nullptr, dwo2 + i*WMAT, nullptr, vb, EE, 1.f, ACT_NONE);
    norm(xrep, vb, nullptr, nullptr, dln2 + i*EE, x, EE, NORM_ADD);    // y
    // FFN
    gemm(x, nullptr, dfg + i*WMAT, nullptr, qb, EE, 1.f, ACT_NONE);
    gemm(x, nullptr, dfp + i*WMAT, nullptr, kb, EE, 1.f, ACT_NONE);
    norm(x, nullptr, qb, kb, dln3 + i*EE, x, EE, NORM_SWIGLU);
  }

  // ---- logits head ----
  gemm(x, nullptr, dhw1, dhb1, t1, EE, 1.f, ACT_GELU);
  norm(t1, nullptr, nullptr, nullptr, dhln, qb, EE, NORM_PLAIN);
  head_kernel<<<MM/4, 256, 0, stream>>>(qb, dhw2, dhb2, logits_out, 16);
}

// Round 5
// 5788.394 us; speedup vs baseline: 8.2047x; 1.6251x over previous
//
#include <hip/hip_runtime.h>
#include <hip/hip_bf16.h>
#include <math.h>

typedef __hip_bfloat16 bf16;
typedef __attribute__((ext_vector_type(8))) short short8;     // 8 bf16 = 4 VGPRs (MFMA frag)
typedef __attribute__((ext_vector_type(4))) float f32x4;      // MFMA acc

#define BB 16
#define SS 512
#define EE 512
#define HH 8
#define DH 64
#define LL 3
#define MM (BB*SS)          // 8192 tokens
#define OBSD 128
#define ACTD 17
#define INV_SQRT_D 0.125f

#define ACT_NONE 0
#define ACT_GELU 1

#define NORM_PLAIN 0
#define NORM_ADD 1
#define NORM_SWIGLU 2

__device__ __forceinline__ float gelu_f(float x){
  float x3 = x*x*x;
  return 0.5f*x*(1.f + tanhf(0.7978845608028654f*(x + 0.044715f*x3)));
}
__device__ __forceinline__ float silu_f(float x){ return x/(1.f+expf(-x)); }
__device__ __forceinline__ float lkappa(int h){ return logf(1.f - exp2f(-5.f - (float)h)); }
__device__ __forceinline__ unsigned short f2bs(float f){   // RNE fp32->bf16 bits
  unsigned int u = __float_as_uint(f);
  u += 0x7FFFu + ((u >> 16) & 1u);
  return (unsigned short)(u >> 16);
}
__device__ __forceinline__ float bs2f(unsigned short u){
  return __uint_as_float(((unsigned int)u) << 16);
}

// ---------------- weight pre-pass: W[K][N=512] fp32 -> Wt[N=512][Kpad] bf16 ----------------
__global__ __launch_bounds__(256) void wtpose_kernel(
    const float* __restrict__ src, unsigned short* __restrict__ dst, int K, int Kpad)
{
  __shared__ float t[32][33];
  const int gx = blockIdx.x, gy = blockIdx.y, gz = blockIdx.z;
  const int tx = threadIdx.x, ty = threadIdx.y;      // block (32,8)
  const float* s = src + (size_t)gz*K*EE;
  unsigned short* d = dst + (size_t)gz*EE*Kpad;
  #pragma unroll
  for (int i = 0; i < 4; ++i){
    int k = gx*32 + ty + i*8, n = gy*32 + tx;
    t[ty+i*8][tx] = (k < K) ? s[(size_t)k*EE + n] : 0.f;
  }
  __syncthreads();
  #pragma unroll
  for (int i = 0; i < 4; ++i){
    int k = gx*32 + tx, n = gy*32 + ty + i*8;
    d[(size_t)n*Kpad + k] = f2bs(t[tx][ty+i*8]);
  }
}

// ---------------- MFMA GEMM: C[8192,512] = act(scale*((A+pe)@W) + bias) ----------------
// A fp32 [M][K], Wt bf16 [512][Kpad], 128x64 tile, BK=32, 4 waves (2Mx2N), 16x16x32 mfma.
__global__ __launch_bounds__(256) void gemm_mfma_kernel(
    const float* __restrict__ A, const unsigned short* __restrict__ peb,
    const unsigned short* __restrict__ Wt, const float* __restrict__ bias,
    float* __restrict__ C, int K, int Kpad, float scale, int act)
{
  __shared__ unsigned short As[128*40];   // [m][k] pitch 40 bf16 (80B rows)
  __shared__ unsigned short Bs[64*40];    // [n][k] pitch 40
  const int bm = blockIdx.y*128, bn = blockIdx.x*64;
  const int tid = threadIdx.x;
  const int lane = tid & 63, wv = tid >> 6;
  const int wr = wv >> 1, wc = wv & 1;
  const bool kvec = ((K & 31) == 0);

  f32x4 acc[4][2];
  #pragma unroll
  for (int i=0;i<4;i++){ acc[i][0]=(f32x4)(0.f); acc[i][1]=(f32x4)(0.f); }

  const int ar = tid >> 1;                 // A stage row 0..127
  const int ah = (tid & 1) * 16;           // col half
  const int br = tid >> 2;                 // B stage row 0..63
  const int bq = (tid & 3) * 8;            // col quarter

  for (int k0 = 0; k0 < Kpad; k0 += 32){
    // ---- stage A (fp32 -> bf16, optional +pe) ----
    float av[16];
    if (kvec){
      const float4* ap = (const float4*)(A + (size_t)(bm+ar)*K + k0 + ah);
      #pragma unroll
      for (int i=0;i<4;i++){
        float4 f = ap[i];
        av[i*4+0]=f.x; av[i*4+1]=f.y; av[i*4+2]=f.z; av[i*4+3]=f.w;
      }
    } else {
      const float* arow = A + (size_t)(bm+ar)*K;
      #pragma unroll
      for (int e=0;e<16;e++){
        int gk = k0 + ah + e;
        av[e] = (gk < K) ? arow[gk] : 0.f;
      }
    }
    if (peb){   // only used when K==512 (pe cols == E)
      const unsigned short* pp = peb + (size_t)(bm+ar)*EE + k0 + ah;
      #pragma unroll
      for (int e=0;e<16;e++) av[e] += bs2f(pp[e]);
    }
    short8 p0, p1;
    #pragma unroll
    for (int e=0;e<8;e++){ p0[e] = (short)f2bs(av[e]); p1[e] = (short)f2bs(av[8+e]); }
    *(short8*)&As[ar*40 + ah]     = p0;
    *(short8*)&As[ar*40 + ah + 8] = p1;
    // ---- stage B (already bf16, transposed) ----
    short8 wfrag = *(const short8*)(Wt + (size_t)(bn+br)*Kpad + k0 + bq);
    *(short8*)&Bs[br*40 + bq] = wfrag;
    __syncthreads();
    // ---- compute ----
    const int m16 = lane & 15, kq = (lane >> 4) * 8;
    short8 a[4], b[2];
    #pragma unroll
    for (int mt=0; mt<4; ++mt)
      a[mt] = *(const short8*)&As[(wr*64 + mt*16 + m16)*40 + kq];
    #pragma unroll
    for (int nt=0; nt<2; ++nt)
      b[nt] = *(const short8*)&Bs[(wc*32 + nt*16 + m16)*40 + kq];
    #pragma unroll
    for (int mt=0; mt<4; ++mt)
      #pragma unroll
      for (int nt=0; nt<2; ++nt)
        acc[mt][nt] = __builtin_amdgcn_mfma_f32_16x16x32_bf16(a[mt], b[nt], acc[mt][nt], 0, 0, 0);
    __syncthreads();
  }
  // ---- epilogue: D row=(lane>>4)*4+j, col=lane&15 ----
  const int rq = (lane >> 4) * 4, cn = lane & 15;
  #pragma unroll
  for (int mt=0; mt<4; ++mt){
    #pragma unroll
    for (int nt=0; nt<2; ++nt){
      int col = bn + wc*32 + nt*16 + cn;
      float bv = bias ? bias[col] : 0.f;
      #pragma unroll
      for (int j=0;j<4;j++){
        int row = bm + wr*64 + mt*16 + rq + j;
        float v = acc[mt][nt][j]*scale + bv;
        if (act==ACT_GELU) v = gelu_f(v);
        C[(size_t)row*EE + col] = v;
      }
    }
  }
}

// ---------------- fused rmsnorm family (fp32 in/out) ----------------
__global__ __launch_bounds__(256) void norm_kernel(
    const float* __restrict__ a, const float* __restrict__ b,
    const float* __restrict__ g, const float* __restrict__ p,
    const float* __restrict__ w, float* __restrict__ outp,
    int cols, int mode)
{
  __shared__ float rowbuf[EE];
  __shared__ float red[4];
  const int row = blockIdx.x, tid = threadIdx.x;
  float ss = 0.f;
  for (int c = tid; c < cols; c += 256){
    size_t off = (size_t)row*cols + c;
    float t = a[off];
    if (mode == NORM_ADD) t += b[off];
    else if (mode == NORM_SWIGLU) t += silu_f(g[off])*p[off];
    rowbuf[c] = t;
    ss += t*t;
  }
  #pragma unroll
  for (int o=32;o;o>>=1) ss += __shfl_down(ss,o);
  if ((tid&63)==0) red[tid>>6]=ss;
  __syncthreads();
  if (tid==0){
    float s = red[0]+red[1]+red[2]+red[3];
    red[0] = 1.f/sqrtf(s/(float)cols + 1e-6f);
  }
  __syncthreads();
  float r = red[0];
  for (int c = tid; c < cols; c += 256)
    outp[(size_t)row*cols + c] = rowbuf[c]*r*w[c];
}

// ---------------- retention core (unchanged from round 4) ----------------
__global__ __launch_bounds__(256) void retention_kernel(
    const float* __restrict__ q, const float* __restrict__ k, const float* __restrict__ v,
    const float* __restrict__ h0, const int* __restrict__ tsi,
    float* __restrict__ outp, int masked)
{
  __shared__ float ksh[64*65];
  __shared__ float vsh[64*65];
  __shared__ float qsh[4][16][64];
  __shared__ float csh[4][16][64];
  __shared__ float tsf[SS];
  const int b = blockIdx.z, h = blockIdx.y;
  const int n0 = blockIdx.x * 64;
  const int tid = threadIdx.x, lane = tid & 63, wv = tid >> 6;
  const float lk = lkappa(h);
  for (int i = tid; i < SS; i += 256) tsf[i] = (float)tsi[b*SS + i];
  const float* h0b = h0 + (size_t)b*(LL*HH*DH*DH) + (size_t)h*(DH*DH);
  for (int i = tid; i < DH*DH; i += 256){
    int d = i >> 6, e = i & 63;
    ksh[e*65 + d] = h0b[i];
  }
  const int rowbase = n0 + wv*16;
  const size_t qbase = ((size_t)b*SS + rowbase)*EE + h*DH;
  #pragma unroll
  for (int r = 0; r < 16; ++r)
    qsh[wv][r][lane] = q[qbase + (size_t)r*EE + lane];
  __syncthreads();
  float acc[16];
  #pragma unroll
  for (int r = 0; r < 16; ++r){
    const float* qr = qsh[wv][r];
    const float* hr = &ksh[lane*65];
    float s = 0.f;
    #pragma unroll
    for (int d = 0; d < 64; d += 4){
      float4 q4 = *(const float4*)&qr[d];
      float4 h4 = *(const float4*)&hr[d];
      s += q4.x*h4.x + q4.y*h4.y + q4.z*h4.z + q4.w*h4.w;
    }
    acc[r] = s * expf(lk*(tsf[rowbase+r]+1.f));
  }
  __syncthreads();
  for (int mc = 0; mc < SS; mc += 64){
    #pragma unroll
    for (int it = 0; it < 4; ++it){
      int i = tid + it*256;
      int m = i >> 4, c = (i & 15)*4;
      size_t goff = ((size_t)b*SS + mc + m)*EE + h*DH + c;
      *(float4*)&ksh[m*65 + c] = *(const float4*)&k[goff];
      *(float4*)&vsh[m*65 + c] = *(const float4*)&v[goff];
    }
    __syncthreads();
    const int mg = mc + lane;
    const float tsm = tsf[mg];
    float cf[16];
    #pragma unroll
    for (int r=0;r<16;r++) cf[r]=0.f;
    const float* kr = &ksh[lane*65];
    #pragma unroll 4
    for (int d = 0; d < 64; d += 4){
      float4 k4 = *(const float4*)&kr[d];
      #pragma unroll
      for (int r = 0; r < 16; ++r){
        float4 q4 = *(const float4*)&qsh[wv][r][d];
        cf[r] += k4.x*q4.x + k4.y*q4.y + k4.z*q4.z + k4.w*q4.w;
      }
    }
    #pragma unroll
    for (int r = 0; r < 16; ++r){
      int n = rowbase + r;
      float diff = tsf[n] - tsm;
      float wgt;
      if (masked) wgt = ((diff > 0.f) || (diff == 0.f && n >= mg)) ? expf(lk*diff) : 0.f;
      else        wgt = expf(lk*fabsf(diff));
      csh[wv][r][lane] = cf[r]*wgt;
    }
    #pragma unroll 4
    for (int m4 = 0; m4 < 64; m4 += 4){
      float v0 = vsh[(m4+0)*65 + lane];
      float v1 = vsh[(m4+1)*65 + lane];
      float v2 = vsh[(m4+2)*65 + lane];
      float v3 = vsh[(m4+3)*65 + lane];
      #pragma unroll
      for (int r = 0; r < 16; ++r){
        float4 c4 = *(const float4*)&csh[wv][r][m4];
        acc[r] += c4.x*v0 + c4.y*v1 + c4.z*v2 + c4.w*v3;
      }
    }
    __syncthreads();
  }
  const size_t obase = ((size_t)b*SS + rowbase)*EE + h*DH;
  #pragma unroll
  for (int r = 0; r < 16; ++r)
    outp[obase + (size_t)r*EE + lane] = acc[r];
}

// ---------------- recurrent state ----------------
__global__ __launch_bounds__(256) void hstate_partial_kernel(
    const float* __restrict__ k, const float* __restrict__ v,
    const int* __restrict__ tsi, const float* __restrict__ tmx,
    float* __restrict__ part)
{
  __shared__ float ksh[64*68];
  __shared__ float vsh[64*64];
  __shared__ float wsh[64];
  const int qr = blockIdx.x, h = blockIdx.y, b = blockIdx.z;
  const int tid = threadIdx.x, lane = tid & 63, wv = tid >> 6;
  const float lk = lkappa(h);
  const float tm = tmx[b];
  float acc[16];
  #pragma unroll
  for (int i=0;i<16;i++) acc[i]=0.f;
  for (int mc = qr*128; mc < qr*128 + 128; mc += 64){
    #pragma unroll
    for (int it=0; it<4; ++it){
      int i = tid + it*256;
      int m = i>>4, c = i&15;
      size_t goff = ((size_t)b*SS + mc + m)*EE + h*DH + c*4;
      *(float4*)&ksh[m*68 + c*4] = *(const float4*)&k[goff];
      *(float4*)&vsh[m*64 + c*4] = *(const float4*)&v[goff];
    }
    if (tid < 64) wsh[tid] = expf(lk*(tm - (float)tsi[b*SS + mc + tid]));
    __syncthreads();
    for (int m = 0; m < 64; ++m){
      float wvv = wsh[m]*vsh[m*64 + lane];
      const float* kr = &ksh[m*68 + wv*16];
      #pragma unroll
      for (int i = 0; i < 16; i += 4){
        float4 k4 = *(const float4*)&kr[i];
        acc[i+0] += k4.x*wvv; acc[i+1] += k4.y*wvv;
        acc[i+2] += k4.z*wvv; acc[i+3] += k4.w*wvv;
      }
    }
    __syncthreads();
  }
  float* pp = part + ((((size_t)b*HH + h)*4 + qr)*DH + wv*16)*DH + lane;
  #pragma unroll
  for (int i=0;i<16;i++) pp[(size_t)i*DH] = acc[i];
}

__global__ __launch_bounds__(256) void hstate_final_kernel(
    const float* __restrict__ part, const float* __restrict__ h0,
    const float* __restrict__ tmx, float* __restrict__ outp)
{
  int idx = blockIdx.x*256 + threadIdx.x;
  int e = idx & 63, d = (idx>>6) & 63, h = (idx>>12) & 7, b = idx >> 15;
  float lk = lkappa(h);
  float dec = expf(lk*(tmx[b] + 1.f));
  const float* pp = part + (((size_t)b*HH + h)*4*DH + d)*DH + e;
  float s = pp[0] + pp[DH*DH] + pp[2*DH*DH] + pp[3*DH*DH];
  size_t off = (size_t)b*(LL*HH*DH*DH) + (size_t)h*DH*DH + d*DH + e;
  outp[off] = dec*h0[off] + s;
}

// ---------------- small helpers ----------------
__global__ void tsmax_kernel(const int* __restrict__ tsi, float* __restrict__ tmx){
  __shared__ int red[4];
  int b = blockIdx.x, tid = threadIdx.x;
  int m = max(tsi[b*SS+tid], tsi[b*SS+256+tid]);
  #pragma unroll
  for (int o=32;o;o>>=1) m = max(m, __shfl_down(m,o));
  if ((tid&63)==0) red[tid>>6]=m;
  __syncthreads();
  if (tid==0) tmx[b] = (float)max(max(red[0],red[1]),max(red[2],red[3]));
}

__global__ void pe_kernel(const int* __restrict__ tsi, unsigned short* __restrict__ peb){
  int idx = blockIdx.x*256 + threadIdx.x;   // MM*EE total
  int row = idx >> 9, j = idx & 511;
  float ts = (float)tsi[row];
  int jj = j & 255;
  float freq = expf(-9.210340371976184f*(float)jj*(1.f/256.f));
  float ang = ts*freq;
  peb[idx] = f2bs((j < 256) ? sinf(ang) : cosf(ang));
}

__global__ __launch_bounds__(256) void head_kernel(
    const float* __restrict__ x, const float* __restrict__ w,
    const float* __restrict__ bias, float* __restrict__ outp, int N)
{
  const int row = blockIdx.x*4 + (threadIdx.x>>6);
  const int lane = threadIdx.x & 63;
  const float* xr = x + (size_t)row*EE;
  float xv[8];
  #pragma unroll
  for (int i=0;i<8;i++) xv[i] = xr[lane + 64*i];
  for (int j=0;j<N;j++){
    float s = 0.f;
    #pragma unroll
    for (int i=0;i<8;i++) s += xv[i]*w[(size_t)(lane+64*i)*N + j];
    #pragma unroll
    for (int o=32;o;o>>=1) s += __shfl_down(s,o);
    if (lane==0) outp[(size_t)row*N + j] = s + bias[j];
  }
}

// ---------------- orchestration ----------------
extern "C" void kernel_launch(void* const* d_in, const int* in_sizes, int n_in,
                              void* d_out, int out_size, void* d_ws, size_t ws_size,
                              hipStream_t stream)
{
  const float* obs     = (const float*)d_in[0];
  const float* action  = (const float*)d_in[1];
  const float* enc_hs  = (const float*)d_in[2];
  const float* dec_hs1 = (const float*)d_in[3];
  const float* dec_hs2 = (const float*)d_in[4];
  const int*   stepc   = (const int*)d_in[5];
  const float* eoln = (const float*)d_in[6];
  const float* eow  = (const float*)d_in[7];
  const float* eln  = (const float*)d_in[8];
  const float* ewq  = (const float*)d_in[9];
  const float* ewk  = (const float*)d_in[10];
  const float* ewv  = (const float*)d_in[11];
  const float* ewo  = (const float*)d_in[12];
  const float* eln1 = (const float*)d_in[13];
  const float* eln2 = (const float*)d_in[14];
  const float* efg  = (const float*)d_in[15];
  const float* efp  = (const float*)d_in[16];
  const float* ehw1 = (const float*)d_in[17];
  const float* ehb1 = (const float*)d_in[18];
  const float* ehln = (const float*)d_in[19];
  const float* ehw2 = (const float*)d_in[20];
  const float* ehb2 = (const float*)d_in[21];
  const float* daw  = (const float*)d_in[22];
  const float* dln  = (const float*)d_in[23];
  const float* dwq1 = (const float*)d_in[24];
  const float* dwk1 = (const float*)d_in[25];
  const float* dwv1 = (const float*)d_in[26];
  const float* dwo1 = (const float*)d_in[27];
  const float* dwq2 = (const float*)d_in[28];
  const float* dwk2 = (const float*)d_in[29];
  const float* dwv2 = (const float*)d_in[30];
  const float* dwo2 = (const float*)d_in[31];
  const float* dln1 = (const float*)d_in[32];
  const float* dln2 = (const float*)d_in[33];
  const float* dln3 = (const float*)d_in[34];
  const float* dfg  = (const float*)d_in[35];
  const float* dfp  = (const float*)d_in[36];
  const float* dhw1 = (const float*)d_in[37];
  const float* dhb1 = (const float*)d_in[38];
  const float* dhln = (const float*)d_in[39];
  const float* dhw2 = (const float*)d_in[40];
  const float* dhb2 = (const float*)d_in[41];

  const size_t BUF = (size_t)MM*EE;            // 4,194,304 floats
  const size_t PART = (size_t)BB*HH*4*DH*DH;   // 2,097,152 floats
  const size_t PEB  = BUF/2;                   // pe as bf16: 2,097,152 float-units
  const size_t WTU  = 6594560/ /*float units*/ 1; // computed below in ushorts; float-units = 6,594,560/2? (see cursor)
  // fp32 buffers: xrep, x, qb, kb, vb, t1  (xn≡x, rp≡t1)
  float* wsf  = (float*)d_ws;
  float* xrep = wsf;
  float* x    = xrep + BUF;
  float* qb   = x    + BUF;
  float* kb   = qb   + BUF;
  float* vb   = kb   + BUF;
  float* t1   = vb   + BUF;
  unsigned short* peb = (unsigned short*)(t1 + BUF);        // MM*EE bf16
  float* part = (float*)(peb + (size_t)MM*EE);
  float* tmx  = part + PART;
  unsigned short* wtc = (unsigned short*)(tmx + 64);

  // weight slots (bf16, transposed, K padded to /32)
  const size_t W55 = (size_t)EE*EE;     // 262144 per 512x512 matrix
  unsigned short* wt_eow  = wtc;                wtc += (size_t)EE*128;
  unsigned short* wt_ewq  = wtc;                wtc += 3*W55;
  unsigned short* wt_ewk  = wtc;                wtc += 3*W55;
  unsigned short* wt_ewv  = wtc;                wtc += 3*W55;
  unsigned short* wt_ewo  = wtc;                wtc += 3*W55;
  unsigned short* wt_efg  = wtc;                wtc += 3*W55;
  unsigned short* wt_efp  = wtc;                wtc += 3*W55;
  unsigned short* wt_ehw1 = wtc;                wtc += W55;
  unsigned short* wt_daw  = wtc;                wtc += (size_t)EE*32;
  unsigned short* wt_dwq1 = wtc;                wtc += 3*W55;
  unsigned short* wt_dwk1 = wtc;                wtc += 3*W55;
  unsigned short* wt_dwv1 = wtc;                wtc += 3*W55;
  unsigned short* wt_dwo1 = wtc;                wtc += 3*W55;
  unsigned short* wt_dwq2 = wtc;                wtc += 3*W55;
  unsigned short* wt_dwk2 = wtc;                wtc += 3*W55;
  unsigned short* wt_dwv2 = wtc;                wtc += 3*W55;
  unsigned short* wt_dwo2 = wtc;                wtc += 3*W55;
  unsigned short* wt_dfg  = wtc;                wtc += 3*W55;
  unsigned short* wt_dfp  = wtc;                wtc += 3*W55;
  unsigned short* wt_dhw1 = wtc;                wtc += W55;
  size_t need = (char*)wtc - (char*)d_ws;
  if (ws_size < need) return;

  float* out        = (float*)d_out;
  float* value_out  = out;
  float* logits_out = out + 8192;
  float* enc_out    = logits_out + (size_t)MM*16;
  float* d1_out     = enc_out + (size_t)BB*LL*HH*DH*DH;
  float* d2_out     = d1_out  + (size_t)BB*LL*HH*DH*DH;

  const size_t HS_L = (size_t)HH*DH*DH;

  auto tpose = [&](const float* src, unsigned short* dst, int K, int Kpad, int nmat){
    wtpose_kernel<<<dim3(Kpad/32, EE/32, nmat), dim3(32,8), 0, stream>>>(src, dst, K, Kpad);
  };
  auto gemm = [&](const float* A, const unsigned short* A2pe, const unsigned short* Wt,
                  const float* bias, float* C, int K, int Kpad, float scale, int act){
    gemm_mfma_kernel<<<dim3(EE/64, MM/128), 256, 0, stream>>>(A, A2pe, Wt, bias, C, K, Kpad, scale, act);
  };
  auto norm = [&](const float* a, const float* b2, const float* g, const float* p,
                  const float* w, float* o, int cols, int mode){
    norm_kernel<<<MM, 256, 0, stream>>>(a, b2, g, p, w, o, cols, mode);
  };
  auto retention = [&](const float* qp, const float* kp, const float* vp,
                       const float* h0, float* o, int masked){
    retention_kernel<<<dim3(8, HH, BB), 256, 0, stream>>>(qp, kp, vp, h0, stepc, o, masked);
  };

  // ---- weight pre-pass (same every call) ----
  tpose(eow,  wt_eow,  128, 128, 1);
  tpose(ewq,  wt_ewq,  512, 512, 3);  tpose(ewk,  wt_ewk,  512, 512, 3);
  tpose(ewv,  wt_ewv,  512, 512, 3);  tpose(ewo,  wt_ewo,  512, 512, 3);
  tpose(efg,  wt_efg,  512, 512, 3);  tpose(efp,  wt_efp,  512, 512, 3);
  tpose(ehw1, wt_ehw1, 512, 512, 1);
  tpose(daw,  wt_daw,  ACTD, 32, 1);
  tpose(dwq1, wt_dwq1, 512, 512, 3);  tpose(dwk1, wt_dwk1, 512, 512, 3);
  tpose(dwv1, wt_dwv1, 512, 512, 3);  tpose(dwo1, wt_dwo1, 512, 512, 3);
  tpose(dwq2, wt_dwq2, 512, 512, 3);  tpose(dwk2, wt_dwk2, 512, 512, 3);
  tpose(dwv2, wt_dwv2, 512, 512, 3);  tpose(dwo2, wt_dwo2, 512, 512, 3);
  tpose(dfg,  wt_dfg,  512, 512, 3);  tpose(dfp,  wt_dfp,  512, 512, 3);
  tpose(dhw1, wt_dhw1, 512, 512, 1);

  // ---- prologue ----
  pe_kernel<<<(MM*EE)/256, 256, 0, stream>>>(stepc, peb);
  tsmax_kernel<<<BB, 256, 0, stream>>>(stepc, tmx);

  // ---- encoder embed: obs_rep = gelu(rmsnorm(obs) @ eow) ----
  norm(obs, nullptr, nullptr, nullptr, eoln, t1, OBSD, NORM_PLAIN);
  gemm(t1, nullptr, wt_eow, nullptr, xrep, OBSD, 128, 1.f, ACT_GELU);

  // ---- encoder layers (xn aliased to x; rp aliased to t1) ----
  float* xn = x;
  for (int i = 0; i < LL; ++i){
    norm(xrep, nullptr, nullptr, nullptr, eln, xn, EE, NORM_PLAIN);
    gemm(xn, peb, wt_ewq + i*W55, nullptr, qb, EE, 512, 1.f, ACT_NONE);
    gemm(xn, peb, wt_ewk + i*W55, nullptr, kb, EE, 512, INV_SQRT_D, ACT_NONE);
    gemm(xn, peb, wt_ewv + i*W55, nullptr, vb, EE, 512, 1.f, ACT_NONE);
    retention(qb, kb, vb, enc_hs + i*HS_L, t1, 0);
    hstate_partial_kernel<<<dim3(4,HH,BB), 256, 0, stream>>>(kb, vb, stepc, tmx, part);
    hstate_final_kernel<<<2048, 256, 0, stream>>>(part, enc_hs + i*HS_L, tmx, enc_out + i*HS_L);
    gemm(t1, nullptr, wt_ewo + i*W55, nullptr, vb, EE, 512, 1.f, ACT_NONE);
    norm(xn, vb, nullptr, nullptr, eln1 + i*EE, t1, EE, NORM_ADD);
    gemm(t1, nullptr, wt_efg + i*W55, nullptr, qb, EE, 512, 1.f, ACT_NONE);
    gemm(t1, nullptr, wt_efp + i*W55, nullptr, kb, EE, 512, 1.f, ACT_NONE);
    norm(t1, nullptr, qb, kb, eln2 + i*EE, xrep, EE, NORM_SWIGLU);
  }

  // ---- value head ----
  gemm(xrep, nullptr, wt_ehw1, ehb1, t1, EE, 512, 1.f, ACT_GELU);
  norm(t1, nullptr, nullptr, nullptr, ehln, qb, EE, NORM_PLAIN);
  head_kernel<<<MM/4, 256, 0, stream>>>(qb, ehw2, ehb2, value_out, 1);

  // ---- decoder embed ----
  gemm(action, nullptr, wt_daw, nullptr, qb, ACTD, 32, 1.f, ACT_GELU);
  norm(qb, nullptr, nullptr, nullptr, dln, x, EE, NORM_PLAIN);

  // ---- decoder layers ----
  for (int i = 0; i < LL; ++i){
    gemm(x, peb, wt_dwq1 + i*W55, nullptr, qb, EE, 512, 1.f, ACT_NONE);
    gemm(x, peb, wt_dwk1 + i*W55, nullptr, kb, EE, 512, INV_SQRT_D, ACT_NONE);
    gemm(x, peb, wt_dwv1 + i*W55, nullptr, vb, EE, 512, 1.f, ACT_NONE);
    retention(qb, kb, vb, dec_hs1 + i*HS_L, t1, 1);
    hstate_partial_kernel<<<dim3(4,HH,BB), 256, 0, stream>>>(kb, vb, stepc, tmx, part);
    hstate_final_kernel<<<2048, 256, 0, stream>>>(part, dec_hs1 + i*HS_L, tmx, d1_out + i*HS_L);
    gemm(t1, nullptr, wt_dwo1 + i*W55, nullptr, vb, EE, 512, 1.f, ACT_NONE);
    norm(x, vb, nullptr, nullptr, dln1 + i*EE, t1, EE, NORM_ADD);      // r -> t1
    gemm(xrep, peb, wt_dwq2 + i*W55, nullptr, qb, EE, 512, 1.f, ACT_NONE);
    gemm(t1,   peb, wt_dwk2 + i*W55, nullptr, kb, EE, 512, INV_SQRT_D, ACT_NONE);
    gemm(t1,   peb, wt_dwv2 + i*W55, nullptr, vb, EE, 512, 1.f, ACT_NONE);
    retention(qb, kb, vb, dec_hs2 + i*HS_L, t1, 1);
    hstate_partial_kernel<<<dim3(4,HH,BB), 256, 0, stream>>>(kb, vb, stepc, tmx, part);
    hstate_final_kernel<<<2048, 256, 0, stream>>>(part, dec_hs2 + i*HS_L, tmx, d2_out + i*HS_L);
    gemm(t1, nullptr, wt_dwo2 + i*W55, nullptr, vb, EE, 512, 1.f, ACT_NONE);
    norm(xrep, vb, nullptr, nullptr, dln2 + i*EE, x, EE, NORM_ADD);    // y -> x
    gemm(x, nullptr, wt_dfg + i*W55, nullptr, qb, EE, 512, 1.f, ACT_NONE);
    gemm(x, nullptr, wt_dfp + i*W55, nullptr, kb, EE, 512, 1.f, ACT_NONE);
    norm(x, nullptr, qb, kb, dln3 + i*EE, x, EE, NORM_SWIGLU);
  }

  // ---- logits head ----
  gemm(x, nullptr, wt_dhw1, dhb1, t1, EE, 512, 1.f, ACT_GELU);
  norm(t1, nullptr, nullptr, nullptr, dhln, qb, EE, NORM_PLAIN);
  head_kernel<<<MM/4, 256, 0, stream>>>(qb, dhw2, dhb2, logits_out, 16);
}

// Round 6
// 2823.104 us; speedup vs baseline: 16.8227x; 2.0504x over previous
//
#include <hip/hip_runtime.h>
#include <hip/hip_bf16.h>
#include <math.h>

typedef __hip_bfloat16 bf16;
typedef __attribute__((ext_vector_type(8))) short short8;     // 8 bf16 = 4 VGPRs (MFMA frag)
typedef __attribute__((ext_vector_type(4))) float f32x4;      // MFMA acc

#define BB 16
#define SS 512
#define EE 512
#define HH 8
#define DH 64
#define LL 3
#define MM (BB*SS)          // 8192 tokens
#define OBSD 128
#define ACTD 17
#define INV_SQRT_D 0.125f

#define ACT_NONE 0
#define ACT_GELU 1

#define NORM_PLAIN 0
#define NORM_ADD 1
#define NORM_SWIGLU 2

__device__ __forceinline__ float gelu_f(float x){
  float x3 = x*x*x;
  return 0.5f*x*(1.f + tanhf(0.7978845608028654f*(x + 0.044715f*x3)));
}
__device__ __forceinline__ float silu_f(float x){ return x/(1.f+expf(-x)); }
__device__ __forceinline__ float lkappa(int h){ return logf(1.f - exp2f(-5.f - (float)h)); }
__device__ __forceinline__ unsigned short f2bs(float f){   // RNE fp32->bf16 bits
  unsigned int u = __float_as_uint(f);
  u += 0x7FFFu + ((u >> 16) & 1u);
  return (unsigned short)(u >> 16);
}
__device__ __forceinline__ float bs2f(unsigned short u){
  return __uint_as_float(((unsigned int)u) << 16);
}

// ---------------- weight pre-pass: W[K][N=512] fp32 -> Wt[N=512][Kpad] bf16 ----------------
__global__ __launch_bounds__(256) void wtpose_kernel(
    const float* __restrict__ src, unsigned short* __restrict__ dst, int K, int Kpad)
{
  __shared__ float t[32][33];
  const int gx = blockIdx.x, gy = blockIdx.y, gz = blockIdx.z;
  const int tx = threadIdx.x, ty = threadIdx.y;      // block (32,8)
  const float* s = src + (size_t)gz*K*EE;
  unsigned short* d = dst + (size_t)gz*EE*Kpad;
  #pragma unroll
  for (int i = 0; i < 4; ++i){
    int k = gx*32 + ty + i*8, n = gy*32 + tx;
    t[ty+i*8][tx] = (k < K) ? s[(size_t)k*EE + n] : 0.f;
  }
  __syncthreads();
  #pragma unroll
  for (int i = 0; i < 4; ++i){
    int k = gx*32 + tx, n = gy*32 + ty + i*8;
    d[(size_t)n*Kpad + k] = f2bs(t[tx][ty+i*8]);
  }
}

// ---------------- MFMA GEMM: C[8192,512] = act(scale*((A+pe)@W) + bias) ----------------
__global__ __launch_bounds__(256) void gemm_mfma_kernel(
    const float* __restrict__ A, const unsigned short* __restrict__ peb,
    const unsigned short* __restrict__ Wt, const float* __restrict__ bias,
    float* __restrict__ C, int K, int Kpad, float scale, int act)
{
  __shared__ unsigned short As[128*40];   // [m][k] pitch 40 bf16
  __shared__ unsigned short Bs[64*40];    // [n][k] pitch 40
  const int bm = blockIdx.y*128, bn = blockIdx.x*64;
  const int tid = threadIdx.x;
  const int lane = tid & 63, wv = tid >> 6;
  const int wr = wv >> 1, wc = wv & 1;
  const bool kvec = ((K & 31) == 0);

  f32x4 acc[4][2];
  #pragma unroll
  for (int i=0;i<4;i++){ acc[i][0]=(f32x4)(0.f); acc[i][1]=(f32x4)(0.f); }

  const int ar = tid >> 1;                 // A stage row 0..127
  const int ah = (tid & 1) * 16;           // col half
  const int br = tid >> 2;                 // B stage row 0..63
  const int bq = (tid & 3) * 8;            // col quarter

  for (int k0 = 0; k0 < Kpad; k0 += 32){
    float av[16];
    if (kvec){
      const float4* ap = (const float4*)(A + (size_t)(bm+ar)*K + k0 + ah);
      #pragma unroll
      for (int i=0;i<4;i++){
        float4 f = ap[i];
        av[i*4+0]=f.x; av[i*4+1]=f.y; av[i*4+2]=f.z; av[i*4+3]=f.w;
      }
    } else {
      const float* arow = A + (size_t)(bm+ar)*K;
      #pragma unroll
      for (int e=0;e<16;e++){
        int gk = k0 + ah + e;
        av[e] = (gk < K) ? arow[gk] : 0.f;
      }
    }
    if (peb){
      const unsigned short* pp = peb + (size_t)(bm+ar)*EE + k0 + ah;
      #pragma unroll
      for (int e=0;e<16;e++) av[e] += bs2f(pp[e]);
    }
    short8 p0, p1;
    #pragma unroll
    for (int e=0;e<8;e++){ p0[e] = (short)f2bs(av[e]); p1[e] = (short)f2bs(av[8+e]); }
    *(short8*)&As[ar*40 + ah]     = p0;
    *(short8*)&As[ar*40 + ah + 8] = p1;
    short8 wfrag = *(const short8*)(Wt + (size_t)(bn+br)*Kpad + k0 + bq);
    *(short8*)&Bs[br*40 + bq] = wfrag;
    __syncthreads();
    const int m16 = lane & 15, kq = (lane >> 4) * 8;
    short8 a[4], b[2];
    #pragma unroll
    for (int mt=0; mt<4; ++mt)
      a[mt] = *(const short8*)&As[(wr*64 + mt*16 + m16)*40 + kq];
    #pragma unroll
    for (int nt=0; nt<2; ++nt)
      b[nt] = *(const short8*)&Bs[(wc*32 + nt*16 + m16)*40 + kq];
    #pragma unroll
    for (int mt=0; mt<4; ++mt)
      #pragma unroll
      for (int nt=0; nt<2; ++nt)
        acc[mt][nt] = __builtin_amdgcn_mfma_f32_16x16x32_bf16(a[mt], b[nt], acc[mt][nt], 0, 0, 0);
    __syncthreads();
  }
  const int rq = (lane >> 4) * 4, cn = lane & 15;
  #pragma unroll
  for (int mt=0; mt<4; ++mt){
    #pragma unroll
    for (int nt=0; nt<2; ++nt){
      int col = bn + wc*32 + nt*16 + cn;
      float bv = bias ? bias[col] : 0.f;
      #pragma unroll
      for (int j=0;j<4;j++){
        int row = bm + wr*64 + mt*16 + rq + j;
        float v = acc[mt][nt][j]*scale + bv;
        if (act==ACT_GELU) v = gelu_f(v);
        C[(size_t)row*EE + col] = v;
      }
    }
  }
}

// ---------------- fused rmsnorm family (fp32 in/out) ----------------
__global__ __launch_bounds__(256) void norm_kernel(
    const float* __restrict__ a, const float* __restrict__ b,
    const float* __restrict__ g, const float* __restrict__ p,
    const float* __restrict__ w, float* __restrict__ outp,
    int cols, int mode)
{
  __shared__ float rowbuf[EE];
  __shared__ float red[4];
  const int row = blockIdx.x, tid = threadIdx.x;
  float ss = 0.f;
  for (int c = tid; c < cols; c += 256){
    size_t off = (size_t)row*cols + c;
    float t = a[off];
    if (mode == NORM_ADD) t += b[off];
    else if (mode == NORM_SWIGLU) t += silu_f(g[off])*p[off];
    rowbuf[c] = t;
    ss += t*t;
  }
  #pragma unroll
  for (int o=32;o;o>>=1) ss += __shfl_down(ss,o);
  if ((tid&63)==0) red[tid>>6]=ss;
  __syncthreads();
  if (tid==0){
    float s = red[0]+red[1]+red[2]+red[3];
    red[0] = 1.f/sqrtf(s/(float)cols + 1e-6f);
  }
  __syncthreads();
  float r = red[0];
  for (int c = tid; c < cols; c += 256)
    outp[(size_t)row*cols + c] = rowbuf[c]*r*w[c];
}

// ---------------- MFMA retention: out = (D∘(QK^T))@V + (Q@h0)*xi ----------------
// grid (4, HH, BB): 128 Q-rows per block, 4 waves x 32 rows. bf16 MFMA, fp32 decay.
__global__ __launch_bounds__(256) void retention_kernel(
    const float* __restrict__ q, const float* __restrict__ k, const float* __restrict__ v,
    const float* __restrict__ h0, const int* __restrict__ tsi,
    float* __restrict__ outp, int masked)
{
  __shared__ unsigned short qsh[128*72];   // Q [n][d] pitch 72 (bf16)
  __shared__ unsigned short ksh[64*72];    // K chunk [m][d] / h0^T [e][d]
  __shared__ unsigned short vsh[64*72];    // V^T chunk [e][m]
  __shared__ unsigned short psh[128*72];   // P per-wave [32 rows][m]
  __shared__ float tsf[SS];
  const int b = blockIdx.z, h = blockIdx.y;
  const int n0 = blockIdx.x * 128;
  const int tid = threadIdx.x, lane = tid & 63, wv = tid >> 6;
  const int quad = lane >> 4, l16 = lane & 15;
  const float lk = lkappa(h);

  for (int i = tid; i < SS; i += 256) tsf[i] = (float)tsi[b*SS + i];

  // stage Q (fp32 -> bf16): thread handles row n=tid>>1, half (tid&1)*32
  {
    const int n = tid >> 1, half = (tid & 1) * 32;
    const float* qr = q + ((size_t)b*SS + n0 + n)*EE + h*DH + half;
    #pragma unroll
    for (int i = 0; i < 4; ++i){
      float4 f0 = *(const float4*)(qr + i*8);
      float4 f1 = *(const float4*)(qr + i*8 + 4);
      short8 pk;
      pk[0]=(short)f2bs(f0.x); pk[1]=(short)f2bs(f0.y); pk[2]=(short)f2bs(f0.z); pk[3]=(short)f2bs(f0.w);
      pk[4]=(short)f2bs(f1.x); pk[5]=(short)f2bs(f1.y); pk[6]=(short)f2bs(f1.z); pk[7]=(short)f2bs(f1.w);
      *(short8*)&qsh[n*72 + half + i*8] = pk;
    }
  }
  // stage h0^T into ksh: h0[d][e] -> ksh[e][d]
  {
    const float* h0b = h0 + (size_t)b*(LL*HH*DH*DH) + (size_t)h*(DH*DH);
    const int d = tid >> 2, eb = (tid & 3) * 16;
    #pragma unroll
    for (int i = 0; i < 4; ++i){
      float4 f = *(const float4*)(h0b + d*DH + eb + i*4);
      ksh[(eb+i*4+0)*72 + d] = f2bs(f.x);
      ksh[(eb+i*4+1)*72 + d] = f2bs(f.y);
      ksh[(eb+i*4+2)*72 + d] = f2bs(f.z);
      ksh[(eb+i*4+3)*72 + d] = f2bs(f.w);
    }
  }
  __syncthreads();

  // row-tile max ts (for masked chunk skip)
  float maxn = fmaxf(tsf[n0 + lane], tsf[n0 + 64 + lane]);
  #pragma unroll
  for (int o=32;o;o>>=1) maxn = fmaxf(maxn, __shfl_xor(maxn, o));

  // Q fragments (persistent)
  const int rowbase = wv*32;
  short8 qa[2][2];
  #pragma unroll
  for (int rt=0; rt<2; ++rt)
    #pragma unroll
    for (int ks=0; ks<2; ++ks)
      qa[rt][ks] = *(const short8*)&qsh[(rowbase + rt*16 + l16)*72 + ks*32 + quad*8];

  // acc init: (Q @ h0) * xi
  f32x4 acc_o[2][4];
  #pragma unroll
  for (int rt=0; rt<2; ++rt){
    #pragma unroll
    for (int et=0; et<4; ++et){
      f32x4 a = (f32x4)(0.f);
      #pragma unroll
      for (int ks=0; ks<2; ++ks){
        short8 hb = *(const short8*)&ksh[(et*16 + l16)*72 + ks*32 + quad*8];
        a = __builtin_amdgcn_mfma_f32_16x16x32_bf16(qa[rt][ks], hb, a, 0, 0, 0);
      }
      acc_o[rt][et] = a;
    }
  }
  #pragma unroll
  for (int rt=0; rt<2; ++rt){
    #pragma unroll
    for (int j=0;j<4;j++){
      float xi = __expf(lk*(tsf[n0 + rowbase + rt*16 + quad*4 + j] + 1.f));
      #pragma unroll
      for (int et=0; et<4; ++et) acc_o[rt][et][j] *= xi;
    }
  }

  for (int mc = 0; mc < SS; mc += 64){
    if (masked){
      float mn = tsf[mc + lane];
      #pragma unroll
      for (int o=32;o;o>>=1) mn = fminf(mn, __shfl_xor(mn, o));
      if (mn > maxn) continue;   // whole chunk strictly in the future -> all weights 0
    }
    __syncthreads();   // previous chunk compute done before restaging
    // stage K [m][d] and V^T [e][m]
    {
      const int m = tid >> 2, cb = (tid & 3) * 16;
      const float* krow = k + ((size_t)b*SS + mc + m)*EE + h*DH + cb;
      const float* vrow = v + ((size_t)b*SS + mc + m)*EE + h*DH + cb;
      #pragma unroll
      for (int i = 0; i < 2; ++i){
        float4 f0 = *(const float4*)(krow + i*8);
        float4 f1 = *(const float4*)(krow + i*8 + 4);
        short8 pk;
        pk[0]=(short)f2bs(f0.x); pk[1]=(short)f2bs(f0.y); pk[2]=(short)f2bs(f0.z); pk[3]=(short)f2bs(f0.w);
        pk[4]=(short)f2bs(f1.x); pk[5]=(short)f2bs(f1.y); pk[6]=(short)f2bs(f1.z); pk[7]=(short)f2bs(f1.w);
        *(short8*)&ksh[m*72 + cb + i*8] = pk;
      }
      #pragma unroll
      for (int i = 0; i < 4; ++i){
        float4 f = *(const float4*)(vrow + i*4);
        vsh[(cb+i*4+0)*72 + m] = f2bs(f.x);
        vsh[(cb+i*4+1)*72 + m] = f2bs(f.y);
        vsh[(cb+i*4+2)*72 + m] = f2bs(f.z);
        vsh[(cb+i*4+3)*72 + m] = f2bs(f.w);
      }
    }
    __syncthreads();
    // S = Q @ K^T for this chunk
    f32x4 sacc[2][4];
    #pragma unroll
    for (int rt=0; rt<2; ++rt)
      #pragma unroll
      for (int mt=0; mt<4; ++mt){
        f32x4 a = (f32x4)(0.f);
        #pragma unroll
        for (int ks=0; ks<2; ++ks){
          short8 kb = *(const short8*)&ksh[(mt*16 + l16)*72 + ks*32 + quad*8];
          a = __builtin_amdgcn_mfma_f32_16x16x32_bf16(qa[rt][ks], kb, a, 0, 0, 0);
        }
        sacc[rt][mt] = a;
      }
    // decay + bf16 P into per-wave LDS
    float tsm[4]; int mg[4];
    #pragma unroll
    for (int mt=0; mt<4; ++mt){ mg[mt] = mc + mt*16 + l16; tsm[mt] = tsf[mg[mt]]; }
    #pragma unroll
    for (int rt=0; rt<2; ++rt){
      #pragma unroll
      for (int j=0;j<4;j++){
        int nloc = rowbase + rt*16 + quad*4 + j;
        int n = n0 + nloc;
        float tsn = tsf[n];
        #pragma unroll
        for (int mt=0; mt<4; ++mt){
          float diff = tsn - tsm[mt];
          float wgt;
          if (masked) wgt = ((diff > 0.f) || (diff == 0.f && n >= mg[mt])) ? __expf(lk*diff) : 0.f;
          else        wgt = __expf(lk*fabsf(diff));
          psh[nloc*72 + mt*16 + l16] = f2bs(sacc[rt][mt][j]*wgt);
        }
      }
    }
    // PV: acc_o += P @ V
    #pragma unroll
    for (int rt=0; rt<2; ++rt){
      #pragma unroll
      for (int ks=0; ks<2; ++ks){
        short8 pa = *(const short8*)&psh[(rowbase + rt*16 + l16)*72 + ks*32 + quad*8];
        #pragma unroll
        for (int et=0; et<4; ++et){
          short8 vb = *(const short8*)&vsh[(et*16 + l16)*72 + ks*32 + quad*8];
          acc_o[rt][et] = __builtin_amdgcn_mfma_f32_16x16x32_bf16(pa, vb, acc_o[rt][et], 0, 0, 0);
        }
      }
    }
  }
  // epilogue
  #pragma unroll
  for (int rt=0; rt<2; ++rt){
    #pragma unroll
    for (int j=0;j<4;j++){
      size_t rbase = ((size_t)b*SS + n0 + rowbase + rt*16 + quad*4 + j)*EE + h*DH;
      #pragma unroll
      for (int et=0; et<4; ++et)
        outp[rbase + et*16 + l16] = acc_o[rt][et][j];
    }
  }
}

// ---------------- recurrent state ----------------
__global__ __launch_bounds__(256) void hstate_partial_kernel(
    const float* __restrict__ k, const float* __restrict__ v,
    const int* __restrict__ tsi, const float* __restrict__ tmx,
    float* __restrict__ part)
{
  __shared__ float ksh[64*68];
  __shared__ float vsh[64*64];
  __shared__ float wsh[64];
  const int qr = blockIdx.x, h = blockIdx.y, b = blockIdx.z;
  const int tid = threadIdx.x, lane = tid & 63, wv = tid >> 6;
  const float lk = lkappa(h);
  const float tm = tmx[b];
  float acc[16];
  #pragma unroll
  for (int i=0;i<16;i++) acc[i]=0.f;
  for (int mc = qr*128; mc < qr*128 + 128; mc += 64){
    #pragma unroll
    for (int it=0; it<4; ++it){
      int i = tid + it*256;
      int m = i>>4, c = i&15;
      size_t goff = ((size_t)b*SS + mc + m)*EE + h*DH + c*4;
      *(float4*)&ksh[m*68 + c*4] = *(const float4*)&k[goff];
      *(float4*)&vsh[m*64 + c*4] = *(const float4*)&v[goff];
    }
    if (tid < 64) wsh[tid] = expf(lk*(tm - (float)tsi[b*SS + mc + tid]));
    __syncthreads();
    for (int m = 0; m < 64; ++m){
      float wvv = wsh[m]*vsh[m*64 + lane];
      const float* kr = &ksh[m*68 + wv*16];
      #pragma unroll
      for (int i = 0; i < 16; i += 4){
        float4 k4 = *(const float4*)&kr[i];
        acc[i+0] += k4.x*wvv; acc[i+1] += k4.y*wvv;
        acc[i+2] += k4.z*wvv; acc[i+3] += k4.w*wvv;
      }
    }
    __syncthreads();
  }
  float* pp = part + ((((size_t)b*HH + h)*4 + qr)*DH + wv*16)*DH + lane;
  #pragma unroll
  for (int i=0;i<16;i++) pp[(size_t)i*DH] = acc[i];
}

__global__ __launch_bounds__(256) void hstate_final_kernel(
    const float* __restrict__ part, const float* __restrict__ h0,
    const float* __restrict__ tmx, float* __restrict__ outp)
{
  int idx = blockIdx.x*256 + threadIdx.x;
  int e = idx & 63, d = (idx>>6) & 63, h = (idx>>12) & 7, b = idx >> 15;
  float lk = lkappa(h);
  float dec = expf(lk*(tmx[b] + 1.f));
  const float* pp = part + (((size_t)b*HH + h)*4*DH + d)*DH + e;
  float s = pp[0] + pp[DH*DH] + pp[2*DH*DH] + pp[3*DH*DH];
  size_t off = (size_t)b*(LL*HH*DH*DH) + (size_t)h*DH*DH + d*DH + e;
  outp[off] = dec*h0[off] + s;
}

// ---------------- small helpers ----------------
__global__ void tsmax_kernel(const int* __restrict__ tsi, float* __restrict__ tmx){
  __shared__ int red[4];
  int b = blockIdx.x, tid = threadIdx.x;
  int m = max(tsi[b*SS+tid], tsi[b*SS+256+tid]);
  #pragma unroll
  for (int o=32;o;o>>=1) m = max(m, __shfl_down(m,o));
  if ((tid&63)==0) red[tid>>6]=m;
  __syncthreads();
  if (tid==0) tmx[b] = (float)max(max(red[0],red[1]),max(red[2],red[3]));
}

__global__ void pe_kernel(const int* __restrict__ tsi, unsigned short* __restrict__ peb){
  int idx = blockIdx.x*256 + threadIdx.x;
  int row = idx >> 9, j = idx & 511;
  float ts = (float)tsi[row];
  int jj = j & 255;
  float freq = expf(-9.210340371976184f*(float)jj*(1.f/256.f));
  float ang = ts*freq;
  peb[idx] = f2bs((j < 256) ? sinf(ang) : cosf(ang));
}

__global__ __launch_bounds__(256) void head_kernel(
    const float* __restrict__ x, const float* __restrict__ w,
    const float* __restrict__ bias, float* __restrict__ outp, int N)
{
  const int row = blockIdx.x*4 + (threadIdx.x>>6);
  const int lane = threadIdx.x & 63;
  const float* xr = x + (size_t)row*EE;
  float xv[8];
  #pragma unroll
  for (int i=0;i<8;i++) xv[i] = xr[lane + 64*i];
  for (int j=0;j<N;j++){
    float s = 0.f;
    #pragma unroll
    for (int i=0;i<8;i++) s += xv[i]*w[(size_t)(lane+64*i)*N + j];
    #pragma unroll
    for (int o=32;o;o>>=1) s += __shfl_down(s,o);
    if (lane==0) outp[(size_t)row*N + j] = s + bias[j];
  }
}

// ---------------- orchestration ----------------
extern "C" void kernel_launch(void* const* d_in, const int* in_sizes, int n_in,
                              void* d_out, int out_size, void* d_ws, size_t ws_size,
                              hipStream_t stream)
{
  const float* obs     = (const float*)d_in[0];
  const float* action  = (const float*)d_in[1];
  const float* enc_hs  = (const float*)d_in[2];
  const float* dec_hs1 = (const float*)d_in[3];
  const float* dec_hs2 = (const float*)d_in[4];
  const int*   stepc   = (const int*)d_in[5];
  const float* eoln = (const float*)d_in[6];
  const float* eow  = (const float*)d_in[7];
  const float* eln  = (const float*)d_in[8];
  const float* ewq  = (const float*)d_in[9];
  const float* ewk  = (const float*)d_in[10];
  const float* ewv  = (const float*)d_in[11];
  const float* ewo  = (const float*)d_in[12];
  const float* eln1 = (const float*)d_in[13];
  const float* eln2 = (const float*)d_in[14];
  const float* efg  = (const float*)d_in[15];
  const float* efp  = (const float*)d_in[16];
  const float* ehw1 = (const float*)d_in[17];
  const float* ehb1 = (const float*)d_in[18];
  const float* ehln = (const float*)d_in[19];
  const float* ehw2 = (const float*)d_in[20];
  const float* ehb2 = (const float*)d_in[21];
  const float* daw  = (const float*)d_in[22];
  const float* dln  = (const float*)d_in[23];
  const float* dwq1 = (const float*)d_in[24];
  const float* dwk1 = (const float*)d_in[25];
  const float* dwv1 = (const float*)d_in[26];
  const float* dwo1 = (const float*)d_in[27];
  const float* dwq2 = (const float*)d_in[28];
  const float* dwk2 = (const float*)d_in[29];
  const float* dwv2 = (const float*)d_in[30];
  const float* dwo2 = (const float*)d_in[31];
  const float* dln1 = (const float*)d_in[32];
  const float* dln2 = (const float*)d_in[33];
  const float* dln3 = (const float*)d_in[34];
  const float* dfg  = (const float*)d_in[35];
  const float* dfp  = (const float*)d_in[36];
  const float* dhw1 = (const float*)d_in[37];
  const float* dhb1 = (const float*)d_in[38];
  const float* dhln = (const float*)d_in[39];
  const float* dhw2 = (const float*)d_in[40];
  const float* dhb2 = (const float*)d_in[41];

  const size_t BUF = (size_t)MM*EE;            // 4,194,304 floats
  const size_t PART = (size_t)BB*HH*4*DH*DH;   // 2,097,152 floats
  float* wsf  = (float*)d_ws;
  float* xrep = wsf;
  float* x    = xrep + BUF;
  float* qb   = x    + BUF;
  float* kb   = qb   + BUF;
  float* vb   = kb   + BUF;
  float* t1   = vb   + BUF;
  unsigned short* peb = (unsigned short*)(t1 + BUF);        // MM*EE bf16
  float* part = (float*)(peb + (size_t)MM*EE);
  float* tmx  = part + PART;
  unsigned short* wtc = (unsigned short*)(tmx + 64);

  const size_t W55 = (size_t)EE*EE;
  unsigned short* wt_eow  = wtc;                wtc += (size_t)EE*128;
  unsigned short* wt_ewq  = wtc;                wtc += 3*W55;
  unsigned short* wt_ewk  = wtc;                wtc += 3*W55;
  unsigned short* wt_ewv  = wtc;                wtc += 3*W55;
  unsigned short* wt_ewo  = wtc;                wtc += 3*W55;
  unsigned short* wt_efg  = wtc;                wtc += 3*W55;
  unsigned short* wt_efp  = wtc;                wtc += 3*W55;
  unsigned short* wt_ehw1 = wtc;                wtc += W55;
  unsigned short* wt_daw  = wtc;                wtc += (size_t)EE*32;
  unsigned short* wt_dwq1 = wtc;                wtc += 3*W55;
  unsigned short* wt_dwk1 = wtc;                wtc += 3*W55;
  unsigned short* wt_dwv1 = wtc;                wtc += 3*W55;
  unsigned short* wt_dwo1 = wtc;                wtc += 3*W55;
  unsigned short* wt_dwq2 = wtc;                wtc += 3*W55;
  unsigned short* wt_dwk2 = wtc;                wtc += 3*W55;
  unsigned short* wt_dwv2 = wtc;                wtc += 3*W55;
  unsigned short* wt_dwo2 = wtc;                wtc += 3*W55;
  unsigned short* wt_dfg  = wtc;                wtc += 3*W55;
  unsigned short* wt_dfp  = wtc;                wtc += 3*W55;
  unsigned short* wt_dhw1 = wtc;                wtc += W55;
  size_t need = (char*)wtc - (char*)d_ws;
  if (ws_size < need) return;

  float* out        = (float*)d_out;
  float* value_out  = out;
  float* logits_out = out + 8192;
  float* enc_out    = logits_out + (size_t)MM*16;
  float* d1_out     = enc_out + (size_t)BB*LL*HH*DH*DH;
  float* d2_out     = d1_out  + (size_t)BB*LL*HH*DH*DH;

  const size_t HS_L = (size_t)HH*DH*DH;

  auto tpose = [&](const float* src, unsigned short* dst, int K, int Kpad, int nmat){
    wtpose_kernel<<<dim3(Kpad/32, EE/32, nmat), dim3(32,8), 0, stream>>>(src, dst, K, Kpad);
  };
  auto gemm = [&](const float* A, const unsigned short* A2pe, const unsigned short* Wt,
                  const float* bias, float* C, int K, int Kpad, float scale, int act){
    gemm_mfma_kernel<<<dim3(EE/64, MM/128), 256, 0, stream>>>(A, A2pe, Wt, bias, C, K, Kpad, scale, act);
  };
  auto norm = [&](const float* a, const float* b2, const float* g, const float* p,
                  const float* w, float* o, int cols, int mode){
    norm_kernel<<<MM, 256, 0, stream>>>(a, b2, g, p, w, o, cols, mode);
  };
  auto retention = [&](const float* qp, const float* kp, const float* vp,
                       const float* h0, float* o, int masked){
    retention_kernel<<<dim3(4, HH, BB), 256, 0, stream>>>(qp, kp, vp, h0, stepc, o, masked);
  };

  // ---- weight pre-pass ----
  tpose(eow,  wt_eow,  128, 128, 1);
  tpose(ewq,  wt_ewq,  512, 512, 3);  tpose(ewk,  wt_ewk,  512, 512, 3);
  tpose(ewv,  wt_ewv,  512, 512, 3);  tpose(ewo,  wt_ewo,  512, 512, 3);
  tpose(efg,  wt_efg,  512, 512, 3);  tpose(efp,  wt_efp,  512, 512, 3);
  tpose(ehw1, wt_ehw1, 512, 512, 1);
  tpose(daw,  wt_daw,  ACTD, 32, 1);
  tpose(dwq1, wt_dwq1, 512, 512, 3);  tpose(dwk1, wt_dwk1, 512, 512, 3);
  tpose(dwv1, wt_dwv1, 512, 512, 3);  tpose(dwo1, wt_dwo1, 512, 512, 3);
  tpose(dwq2, wt_dwq2, 512, 512, 3);  tpose(dwk2, wt_dwk2, 512, 512, 3);
  tpose(dwv2, wt_dwv2, 512, 512, 3);  tpose(dwo2, wt_dwo2, 512, 512, 3);
  tpose(dfg,  wt_dfg,  512, 512, 3);  tpose(dfp,  wt_dfp,  512, 512, 3);
  tpose(dhw1, wt_dhw1, 512, 512, 1);

  // ---- prologue ----
  pe_kernel<<<(MM*EE)/256, 256, 0, stream>>>(stepc, peb);
  tsmax_kernel<<<BB, 256, 0, stream>>>(stepc, tmx);

  // ---- encoder embed ----
  norm(obs, nullptr, nullptr, nullptr, eoln, t1, OBSD, NORM_PLAIN);
  gemm(t1, nullptr, wt_eow, nullptr, xrep, OBSD, 128, 1.f, ACT_GELU);

  // ---- encoder layers ----
  float* xn = x;
  for (int i = 0; i < LL; ++i){
    norm(xrep, nullptr, nullptr, nullptr, eln, xn, EE, NORM_PLAIN);
    gemm(xn, peb, wt_ewq + i*W55, nullptr, qb, EE, 512, 1.f, ACT_NONE);
    gemm(xn, peb, wt_ewk + i*W55, nullptr, kb, EE, 512, INV_SQRT_D, ACT_NONE);
    gemm(xn, peb, wt_ewv + i*W55, nullptr, vb, EE, 512, 1.f, ACT_NONE);
    retention(qb, kb, vb, enc_hs + i*HS_L, t1, 0);
    hstate_partial_kernel<<<dim3(4,HH,BB), 256, 0, stream>>>(kb, vb, stepc, tmx, part);
    hstate_final_kernel<<<2048, 256, 0, stream>>>(part, enc_hs + i*HS_L, tmx, enc_out + i*HS_L);
    gemm(t1, nullptr, wt_ewo + i*W55, nullptr, vb, EE, 512, 1.f, ACT_NONE);
    norm(xn, vb, nullptr, nullptr, eln1 + i*EE, t1, EE, NORM_ADD);
    gemm(t1, nullptr, wt_efg + i*W55, nullptr, qb, EE, 512, 1.f, ACT_NONE);
    gemm(t1, nullptr, wt_efp + i*W55, nullptr, kb, EE, 512, 1.f, ACT_NONE);
    norm(t1, nullptr, qb, kb, eln2 + i*EE, xrep, EE, NORM_SWIGLU);
  }

  // ---- value head ----
  gemm(xrep, nullptr, wt_ehw1, ehb1, t1, EE, 512, 1.f, ACT_GELU);
  norm(t1, nullptr, nullptr, nullptr, ehln, qb, EE, NORM_PLAIN);
  head_kernel<<<MM/4, 256, 0, stream>>>(qb, ehw2, ehb2, value_out, 1);

  // ---- decoder embed ----
  gemm(action, nullptr, wt_daw, nullptr, qb, ACTD, 32, 1.f, ACT_GELU);
  norm(qb, nullptr, nullptr, nullptr, dln, x, EE, NORM_PLAIN);

  // ---- decoder layers ----
  for (int i = 0; i < LL; ++i){
    gemm(x, peb, wt_dwq1 + i*W55, nullptr, qb, EE, 512, 1.f, ACT_NONE);
    gemm(x, peb, wt_dwk1 + i*W55, nullptr, kb, EE, 512, INV_SQRT_D, ACT_NONE);
    gemm(x, peb, wt_dwv1 + i*W55, nullptr, vb, EE, 512, 1.f, ACT_NONE);
    retention(qb, kb, vb, dec_hs1 + i*HS_L, t1, 1);
    hstate_partial_kernel<<<dim3(4,HH,BB), 256, 0, stream>>>(kb, vb, stepc, tmx, part);
    hstate_final_kernel<<<2048, 256, 0, stream>>>(part, dec_hs1 + i*HS_L, tmx, d1_out + i*HS_L);
    gemm(t1, nullptr, wt_dwo1 + i*W55, nullptr, vb, EE, 512, 1.f, ACT_NONE);
    norm(x, vb, nullptr, nullptr, dln1 + i*EE, t1, EE, NORM_ADD);      // r -> t1
    gemm(xrep, peb, wt_dwq2 + i*W55, nullptr, qb, EE, 512, 1.f, ACT_NONE);
    gemm(t1,   peb, wt_dwk2 + i*W55, nullptr, kb, EE, 512, INV_SQRT_D, ACT_NONE);
    gemm(t1,   peb, wt_dwv2 + i*W55, nullptr, vb, EE, 512, 1.f, ACT_NONE);
    retention(qb, kb, vb, dec_hs2 + i*HS_L, t1, 1);
    hstate_partial_kernel<<<dim3(4,HH,BB), 256, 0, stream>>>(kb, vb, stepc, tmx, part);
    hstate_final_kernel<<<2048, 256, 0, stream>>>(part, dec_hs2 + i*HS_L, tmx, d2_out + i*HS_L);
    gemm(t1, nullptr, wt_dwo2 + i*W55, nullptr, vb, EE, 512, 1.f, ACT_NONE);
    norm(xrep, vb, nullptr, nullptr, dln2 + i*EE, x, EE, NORM_ADD);    // y -> x
    gemm(x, nullptr, wt_dfg + i*W55, nullptr, qb, EE, 512, 1.f, ACT_NONE);
    gemm(x, nullptr, wt_dfp + i*W55, nullptr, kb, EE, 512, 1.f, ACT_NONE);
    norm(x, nullptr, qb, kb, dln3 + i*EE, x, EE, NORM_SWIGLU);
  }

  // ---- logits head ----
  gemm(x, nullptr, wt_dhw1, dhb1, t1, EE, 512, 1.f, ACT_GELU);
  norm(t1, nullptr, nullptr, nullptr, dhln, qb, EE, NORM_PLAIN);
  head_kernel<<<MM/4, 256, 0, stream>>>(qb, dhw2, dhb2, logits_out, 16);
}

// Round 7
// 1791.594 us; speedup vs baseline: 26.5083x; 1.5757x over previous
//
#include <hip/hip_runtime.h>
#include <hip/hip_bf16.h>
#include <math.h>

typedef __attribute__((ext_vector_type(8))) short short8;     // 8 bf16 = 4 VGPRs
typedef __attribute__((ext_vector_type(4))) float f32x4;

#define BB 16
#define SS 512
#define EE 512
#define HH 8
#define DH 64
#define LL 3
#define MM (BB*SS)
#define OBSD 128
#define ACTD 17
#define INV_SQRT_D 0.125f

#define ACT_NONE 0
#define ACT_GELU 1

#define NORM_PLAIN 0
#define NORM_ADD 1
#define NORM_SWIGLU 2

__device__ __forceinline__ float gelu_f(float x){
  float x3 = x*x*x;
  return 0.5f*x*(1.f + tanhf(0.7978845608028654f*(x + 0.044715f*x3)));
}
__device__ __forceinline__ float silu_f(float x){ return x/(1.f+expf(-x)); }
__device__ __forceinline__ float lkappa(int h){ return logf(1.f - exp2f(-5.f - (float)h)); }
__device__ __forceinline__ unsigned short f2bs(float f){
  unsigned int u = __float_as_uint(f);
  u += 0x7FFFu + ((u >> 16) & 1u);
  return (unsigned short)(u >> 16);
}
__device__ __forceinline__ float bs2f(unsigned short u){
  return __uint_as_float(((unsigned int)u) << 16);
}

// ---------------- weight transpose: W[K][512] fp32 -> Wt[512][Kpad] bf16 ----------------
__global__ __launch_bounds__(256) void wtpose_kernel(
    const float* __restrict__ src, unsigned short* __restrict__ dst, int K, int Kpad)
{
  __shared__ float t[32][33];
  const int gx = blockIdx.x, gy = blockIdx.y;
  const int tx = threadIdx.x, ty = threadIdx.y;
  #pragma unroll
  for (int i = 0; i < 4; ++i){
    int k = gx*32 + ty + i*8, n = gy*32 + tx;
    t[ty+i*8][tx] = (k < K) ? src[(size_t)k*EE + n] : 0.f;
  }
  __syncthreads();
  #pragma unroll
  for (int i = 0; i < 4; ++i){
    int k = gx*32 + tx, n = gy*32 + ty + i*8;
    dst[(size_t)n*Kpad + k] = f2bs(t[tx][ty+i*8]);
  }
}

struct TP50 { const float* s[50]; unsigned short* d[50]; };
__global__ __launch_bounds__(256) void wtpose_batch_kernel(TP50 tp)
{
  __shared__ float t[32][33];
  const float* src = tp.s[blockIdx.z];
  unsigned short* dst = tp.d[blockIdx.z];
  const int gx = blockIdx.x, gy = blockIdx.y;
  const int tx = threadIdx.x, ty = threadIdx.y;
  #pragma unroll
  for (int i = 0; i < 4; ++i){
    int k = gx*32 + ty + i*8, n = gy*32 + tx;
    t[ty+i*8][tx] = src[(size_t)k*EE + n];
  }
  __syncthreads();
  #pragma unroll
  for (int i = 0; i < 4; ++i){
    int k = gx*32 + tx, n = gy*32 + ty + i*8;
    dst[(size_t)n*EE + k] = f2bs(t[tx][ty+i*8]);
  }
}

// ---------------- MFMA GEMM: C[8192,512] fp32 = act(scale*(A_b@W) + bias), A bf16 ----------------
// tile 128x64, BK=64, 4 waves (2Mx2N). LDS pitch 72 (bank-safe).
__global__ __launch_bounds__(256) void gemm_b_kernel(
    const unsigned short* __restrict__ A, const unsigned short* __restrict__ Wt,
    const float* __restrict__ bias, float* __restrict__ C,
    int Kpad, float scale, int act)
{
  __shared__ unsigned short As[128*72];
  __shared__ unsigned short Bs[64*72];
  const int bm = blockIdx.y*128, bn = blockIdx.x*64;
  const int tid = threadIdx.x, lane = tid & 63, wv = tid >> 6;
  const int wr = wv >> 1, wc = wv & 1;
  const int l16 = lane & 15, quad = lane >> 4;

  f32x4 acc[4][2];
  #pragma unroll
  for (int i=0;i<4;i++){ acc[i][0]=(f32x4)(0.f); acc[i][1]=(f32x4)(0.f); }

  const int arow = tid >> 1, acol = (tid & 1)*32;
  const int brow = tid >> 2, bcol = (tid & 3)*16;

  for (int k0 = 0; k0 < Kpad; k0 += 64){
    const unsigned short* ag = A + (size_t)(bm+arow)*Kpad + k0 + acol;
    #pragma unroll
    for (int i=0;i<4;i++)
      *(short8*)&As[arow*72 + acol + i*8] = *(const short8*)(ag + i*8);
    const unsigned short* bg = Wt + (size_t)(bn+brow)*Kpad + k0 + bcol;
    #pragma unroll
    for (int i=0;i<2;i++)
      *(short8*)&Bs[brow*72 + bcol + i*8] = *(const short8*)(bg + i*8);
    __syncthreads();
    short8 af[4][2], bf[2][2];
    #pragma unroll
    for (int mt=0; mt<4; ++mt)
      #pragma unroll
      for (int ks=0; ks<2; ++ks)
        af[mt][ks] = *(const short8*)&As[(wr*64 + mt*16 + l16)*72 + ks*32 + quad*8];
    #pragma unroll
    for (int nt=0; nt<2; ++nt)
      #pragma unroll
      for (int ks=0; ks<2; ++ks)
        bf[nt][ks] = *(const short8*)&Bs[(wc*32 + nt*16 + l16)*72 + ks*32 + quad*8];
    #pragma unroll
    for (int ks=0; ks<2; ++ks)
      #pragma unroll
      for (int mt=0; mt<4; ++mt)
        #pragma unroll
        for (int nt=0; nt<2; ++nt)
          acc[mt][nt] = __builtin_amdgcn_mfma_f32_16x16x32_bf16(af[mt][ks], bf[nt][ks], acc[mt][nt], 0, 0, 0);
    __syncthreads();
  }
  #pragma unroll
  for (int mt=0; mt<4; ++mt){
    #pragma unroll
    for (int nt=0; nt<2; ++nt){
      int col = bn + wc*32 + nt*16 + l16;
      float bv = bias ? bias[col] : 0.f;
      #pragma unroll
      for (int j=0;j<4;j++){
        int row = bm + wr*64 + mt*16 + quad*4 + j;
        float v = acc[mt][nt][j]*scale + bv;
        if (act==ACT_GELU) v = gelu_f(v);
        C[(size_t)row*EE + col] = v;
      }
    }
  }
}

// ---------------- rmsnorm: mixed fp32/bf16 input -> bf16 out (+ optional out+pe) ----------------
__global__ __launch_bounds__(256) void norm_b_kernel(
    const float* __restrict__ af, const unsigned short* __restrict__ ab,
    const float* __restrict__ res, const float* __restrict__ g, const float* __restrict__ p,
    const float* __restrict__ w, unsigned short* __restrict__ o1,
    unsigned short* __restrict__ o2, const unsigned short* __restrict__ peb,
    int mode)
{
  __shared__ float red[4];
  const int row = blockIdx.x, tid = threadIdx.x;
  const size_t base = (size_t)row*EE + tid*2;
  float t0, t1;
  if (ab){
    unsigned int av = *(const unsigned int*)&ab[base];
    t0 = bs2f((unsigned short)(av & 0xffffu));
    t1 = bs2f((unsigned short)(av >> 16));
  } else {
    float2 av = *(const float2*)&af[base];
    t0 = av.x; t1 = av.y;
  }
  if (mode == NORM_ADD){
    float2 rv = *(const float2*)&res[base];
    t0 += rv.x; t1 += rv.y;
  } else if (mode == NORM_SWIGLU){
    float2 gv = *(const float2*)&g[base];
    float2 pv = *(const float2*)&p[base];
    t0 += silu_f(gv.x)*pv.x; t1 += silu_f(gv.y)*pv.y;
  }
  float ss = t0*t0 + t1*t1;
  #pragma unroll
  for (int o=32;o;o>>=1) ss += __shfl_down(ss,o);
  if ((tid&63)==0) red[tid>>6]=ss;
  __syncthreads();
  if (tid==0) red[0] = 1.f/sqrtf((red[0]+red[1]+red[2]+red[3])/(float)EE + 1e-6f);
  __syncthreads();
  float r = red[0];
  float2 wv2 = *(const float2*)&w[tid*2];
  float y0 = t0*r*wv2.x, y1 = t1*r*wv2.y;
  unsigned int pk = (unsigned int)f2bs(y0) | ((unsigned int)f2bs(y1) << 16);
  *(unsigned int*)&o1[base] = pk;
  if (o2){
    unsigned int pv = *(const unsigned int*)&peb[base];
    float z0 = y0 + bs2f((unsigned short)(pv & 0xffffu));
    float z1 = y1 + bs2f((unsigned short)(pv >> 16));
    *(unsigned int*)&o2[base] = (unsigned int)f2bs(z0) | ((unsigned int)f2bs(z1) << 16);
  }
}

// obs norm: fp32 [MM][128] -> bf16 [MM][128]
__global__ __launch_bounds__(128) void norm_obs_kernel(
    const float* __restrict__ a, const float* __restrict__ w, unsigned short* __restrict__ o)
{
  __shared__ float red[2];
  const int row = blockIdx.x, tid = threadIdx.x;
  float t = a[(size_t)row*OBSD + tid];
  float ss = t*t;
  #pragma unroll
  for (int off=32;off;off>>=1) ss += __shfl_down(ss,off);
  if ((tid&63)==0) red[tid>>6]=ss;
  __syncthreads();
  if (tid==0) red[0] = 1.f/sqrtf((red[0]+red[1])/(float)OBSD + 1e-6f);
  __syncthreads();
  o[(size_t)row*OBSD + tid] = f2bs(t*red[0]*w[tid]);
}

// action embed: fp32 [MM][17] -> bf16 [MM][64] zero-padded
__global__ __launch_bounds__(256) void act_embed_kernel(
    const float* __restrict__ a, unsigned short* __restrict__ o)
{
  int idx = blockIdx.x*256 + threadIdx.x;   // MM*64
  int row = idx >> 6, col = idx & 63;
  o[idx] = (col < ACTD) ? f2bs(a[(size_t)row*ACTD + col]) : 0;
}

// ---------------- MFMA retention (fp32 q,k,v in; bf16 out) ----------------
__global__ __launch_bounds__(256) void retention_kernel(
    const float* __restrict__ q, const float* __restrict__ k, const float* __restrict__ v,
    const float* __restrict__ h0, const int* __restrict__ tsi,
    unsigned short* __restrict__ outp, int masked)
{
  __shared__ unsigned short qsh[128*72];
  __shared__ unsigned short ksh[64*72];
  __shared__ unsigned short vsh[64*72];
  __shared__ unsigned short psh[128*72];
  __shared__ float tsf[SS];
  const int b = blockIdx.z, h = blockIdx.y;
  const int n0 = blockIdx.x * 128;
  const int tid = threadIdx.x, lane = tid & 63, wv = tid >> 6;
  const int quad = lane >> 4, l16 = lane & 15;
  const float lk = lkappa(h);

  for (int i = tid; i < SS; i += 256) tsf[i] = (float)tsi[b*SS + i];
  {
    const int n = tid >> 1, half = (tid & 1) * 32;
    const float* qr = q + ((size_t)b*SS + n0 + n)*EE + h*DH + half;
    #pragma unroll
    for (int i = 0; i < 4; ++i){
      float4 f0 = *(const float4*)(qr + i*8);
      float4 f1 = *(const float4*)(qr + i*8 + 4);
      short8 pk;
      pk[0]=(short)f2bs(f0.x); pk[1]=(short)f2bs(f0.y); pk[2]=(short)f2bs(f0.z); pk[3]=(short)f2bs(f0.w);
      pk[4]=(short)f2bs(f1.x); pk[5]=(short)f2bs(f1.y); pk[6]=(short)f2bs(f1.z); pk[7]=(short)f2bs(f1.w);
      *(short8*)&qsh[n*72 + half + i*8] = pk;
    }
  }
  {
    const float* h0b = h0 + (size_t)b*(LL*HH*DH*DH) + (size_t)h*(DH*DH);
    const int d = tid >> 2, eb = (tid & 3) * 16;
    #pragma unroll
    for (int i = 0; i < 4; ++i){
      float4 f = *(const float4*)(h0b + d*DH + eb + i*4);
      ksh[(eb+i*4+0)*72 + d] = f2bs(f.x);
      ksh[(eb+i*4+1)*72 + d] = f2bs(f.y);
      ksh[(eb+i*4+2)*72 + d] = f2bs(f.z);
      ksh[(eb+i*4+3)*72 + d] = f2bs(f.w);
    }
  }
  __syncthreads();

  float maxn = fmaxf(tsf[n0 + lane], tsf[n0 + 64 + lane]);
  #pragma unroll
  for (int o=32;o;o>>=1) maxn = fmaxf(maxn, __shfl_xor(maxn, o));

  const int rowbase = wv*32;
  short8 qa[2][2];
  #pragma unroll
  for (int rt=0; rt<2; ++rt)
    #pragma unroll
    for (int ks=0; ks<2; ++ks)
      qa[rt][ks] = *(const short8*)&qsh[(rowbase + rt*16 + l16)*72 + ks*32 + quad*8];

  f32x4 acc_o[2][4];
  #pragma unroll
  for (int rt=0; rt<2; ++rt){
    #pragma unroll
    for (int et=0; et<4; ++et){
      f32x4 a = (f32x4)(0.f);
      #pragma unroll
      for (int ks=0; ks<2; ++ks){
        short8 hb = *(const short8*)&ksh[(et*16 + l16)*72 + ks*32 + quad*8];
        a = __builtin_amdgcn_mfma_f32_16x16x32_bf16(qa[rt][ks], hb, a, 0, 0, 0);
      }
      acc_o[rt][et] = a;
    }
  }
  #pragma unroll
  for (int rt=0; rt<2; ++rt){
    #pragma unroll
    for (int j=0;j<4;j++){
      float xi = __expf(lk*(tsf[n0 + rowbase + rt*16 + quad*4 + j] + 1.f));
      #pragma unroll
      for (int et=0; et<4; ++et) acc_o[rt][et][j] *= xi;
    }
  }

  for (int mc = 0; mc < SS; mc += 64){
    if (masked){
      float mn = tsf[mc + lane];
      #pragma unroll
      for (int o=32;o;o>>=1) mn = fminf(mn, __shfl_xor(mn, o));
      if (mn > maxn) continue;
    }
    __syncthreads();
    {
      const int m = tid >> 2, cb = (tid & 3) * 16;
      const float* krow = k + ((size_t)b*SS + mc + m)*EE + h*DH + cb;
      const float* vrow = v + ((size_t)b*SS + mc + m)*EE + h*DH + cb;
      #pragma unroll
      for (int i = 0; i < 2; ++i){
        float4 f0 = *(const float4*)(krow + i*8);
        float4 f1 = *(const float4*)(krow + i*8 + 4);
        short8 pk;
        pk[0]=(short)f2bs(f0.x); pk[1]=(short)f2bs(f0.y); pk[2]=(short)f2bs(f0.z); pk[3]=(short)f2bs(f0.w);
        pk[4]=(short)f2bs(f1.x); pk[5]=(short)f2bs(f1.y); pk[6]=(short)f2bs(f1.z); pk[7]=(short)f2bs(f1.w);
        *(short8*)&ksh[m*72 + cb + i*8] = pk;
      }
      #pragma unroll
      for (int i = 0; i < 4; ++i){
        float4 f = *(const float4*)(vrow + i*4);
        vsh[(cb+i*4+0)*72 + m] = f2bs(f.x);
        vsh[(cb+i*4+1)*72 + m] = f2bs(f.y);
        vsh[(cb+i*4+2)*72 + m] = f2bs(f.z);
        vsh[(cb+i*4+3)*72 + m] = f2bs(f.w);
      }
    }
    __syncthreads();
    f32x4 sacc[2][4];
    #pragma unroll
    for (int rt=0; rt<2; ++rt)
      #pragma unroll
      for (int mt=0; mt<4; ++mt){
        f32x4 a = (f32x4)(0.f);
        #pragma unroll
        for (int ks=0; ks<2; ++ks){
          short8 kb = *(const short8*)&ksh[(mt*16 + l16)*72 + ks*32 + quad*8];
          a = __builtin_amdgcn_mfma_f32_16x16x32_bf16(qa[rt][ks], kb, a, 0, 0, 0);
        }
        sacc[rt][mt] = a;
      }
    float tsm[4]; int mg[4];
    #pragma unroll
    for (int mt=0; mt<4; ++mt){ mg[mt] = mc + mt*16 + l16; tsm[mt] = tsf[mg[mt]]; }
    #pragma unroll
    for (int rt=0; rt<2; ++rt){
      #pragma unroll
      for (int j=0;j<4;j++){
        int nloc = rowbase + rt*16 + quad*4 + j;
        int n = n0 + nloc;
        float tsn = tsf[n];
        #pragma unroll
        for (int mt=0; mt<4; ++mt){
          float diff = tsn - tsm[mt];
          float wgt;
          if (masked) wgt = ((diff > 0.f) || (diff == 0.f && n >= mg[mt])) ? __expf(lk*diff) : 0.f;
          else        wgt = __expf(lk*fabsf(diff));
          psh[nloc*72 + mt*16 + l16] = f2bs(sacc[rt][mt][j]*wgt);
        }
      }
    }
    #pragma unroll
    for (int rt=0; rt<2; ++rt){
      #pragma unroll
      for (int ks=0; ks<2; ++ks){
        short8 pa = *(const short8*)&psh[(rowbase + rt*16 + l16)*72 + ks*32 + quad*8];
        #pragma unroll
        for (int et=0; et<4; ++et){
          short8 vb = *(const short8*)&vsh[(et*16 + l16)*72 + ks*32 + quad*8];
          acc_o[rt][et] = __builtin_amdgcn_mfma_f32_16x16x32_bf16(pa, vb, acc_o[rt][et], 0, 0, 0);
        }
      }
    }
  }
  #pragma unroll
  for (int rt=0; rt<2; ++rt){
    #pragma unroll
    for (int j=0;j<4;j++){
      size_t rbase = ((size_t)b*SS + n0 + rowbase + rt*16 + quad*4 + j)*EE + h*DH;
      #pragma unroll
      for (int et=0; et<4; ++et)
        outp[rbase + et*16 + l16] = f2bs(acc_o[rt][et][j]);
    }
  }
}

// ---------------- recurrent state (fp32 k,v) ----------------
__global__ __launch_bounds__(256) void hstate_partial_kernel(
    const float* __restrict__ k, const float* __restrict__ v,
    const int* __restrict__ tsi, const float* __restrict__ tmx,
    float* __restrict__ part)
{
  __shared__ float ksh[64*68];
  __shared__ float vsh[64*64];
  __shared__ float wsh[64];
  const int qr = blockIdx.x, h = blockIdx.y, b = blockIdx.z;
  const int tid = threadIdx.x, lane = tid & 63, wv = tid >> 6;
  const float lk = lkappa(h);
  const float tm = tmx[b];
  float acc[16];
  #pragma unroll
  for (int i=0;i<16;i++) acc[i]=0.f;
  for (int mc = qr*128; mc < qr*128 + 128; mc += 64){
    #pragma unroll
    for (int it=0; it<4; ++it){
      int i = tid + it*256;
      int m = i>>4, c = i&15;
      size_t goff = ((size_t)b*SS + mc + m)*EE + h*DH + c*4;
      *(float4*)&ksh[m*68 + c*4] = *(const float4*)&k[goff];
      *(float4*)&vsh[m*64 + c*4] = *(const float4*)&v[goff];
    }
    if (tid < 64) wsh[tid] = expf(lk*(tm - (float)tsi[b*SS + mc + tid]));
    __syncthreads();
    for (int m = 0; m < 64; ++m){
      float wvv = wsh[m]*vsh[m*64 + lane];
      const float* kr = &ksh[m*68 + wv*16];
      #pragma unroll
      for (int i = 0; i < 16; i += 4){
        float4 k4 = *(const float4*)&kr[i];
        acc[i+0] += k4.x*wvv; acc[i+1] += k4.y*wvv;
        acc[i+2] += k4.z*wvv; acc[i+3] += k4.w*wvv;
      }
    }
    __syncthreads();
  }
  float* pp = part + ((((size_t)b*HH + h)*4 + qr)*DH + wv*16)*DH + lane;
  #pragma unroll
  for (int i=0;i<16;i++) pp[(size_t)i*DH] = acc[i];
}

__global__ __launch_bounds__(256) void hstate_final_kernel(
    const float* __restrict__ part, const float* __restrict__ h0,
    const float* __restrict__ tmx, float* __restrict__ outp)
{
  int idx = blockIdx.x*256 + threadIdx.x;
  int e = idx & 63, d = (idx>>6) & 63, h = (idx>>12) & 7, b = idx >> 15;
  float lk = lkappa(h);
  float dec = expf(lk*(tmx[b] + 1.f));
  const float* pp = part + (((size_t)b*HH + h)*4*DH + d)*DH + e;
  float s = pp[0] + pp[DH*DH] + pp[2*DH*DH] + pp[3*DH*DH];
  size_t off = (size_t)b*(LL*HH*DH*DH) + (size_t)h*DH*DH + d*DH + e;
  outp[off] = dec*h0[off] + s;
}

// ---------------- small helpers ----------------
__global__ void tsmax_kernel(const int* __restrict__ tsi, float* __restrict__ tmx){
  __shared__ int red[4];
  int b = blockIdx.x, tid = threadIdx.x;
  int m = max(tsi[b*SS+tid], tsi[b*SS+256+tid]);
  #pragma unroll
  for (int o=32;o;o>>=1) m = max(m, __shfl_down(m,o));
  if ((tid&63)==0) red[tid>>6]=m;
  __syncthreads();
  if (tid==0) tmx[b] = (float)max(max(red[0],red[1]),max(red[2],red[3]));
}

__global__ void pe_kernel(const int* __restrict__ tsi, unsigned short* __restrict__ peb){
  int idx = blockIdx.x*256 + threadIdx.x;
  int row = idx >> 9, j = idx & 511;
  float ts = (float)tsi[row];
  int jj = j & 255;
  float freq = expf(-9.210340371976184f*(float)jj*(1.f/256.f));
  float ang = ts*freq;
  peb[idx] = f2bs((j < 256) ? sinf(ang) : cosf(ang));
}

// value head: N=1, x bf16, w fp32. 8 lanes per row.
__global__ __launch_bounds__(256) void value_head_kernel(
    const unsigned short* __restrict__ x, const float* __restrict__ w,
    const float* __restrict__ bias, float* __restrict__ outp)
{
  const int tid = threadIdx.x, lane = tid & 63, wv = tid >> 6;
  const int r8 = lane >> 3, seg = lane & 7;
  const int row = blockIdx.x*32 + wv*8 + r8;
  const unsigned short* xr = x + (size_t)row*EE + seg*64;
  const float* wr = w + seg*64;
  float s = 0.f;
  #pragma unroll
  for (int i = 0; i < 8; ++i){
    short8 xv = *(const short8*)(xr + i*8);
    #pragma unroll
    for (int e = 0; e < 8; ++e)
      s += bs2f((unsigned short)xv[e]) * wr[i*8 + e];
  }
  s += __shfl_xor(s, 1); s += __shfl_xor(s, 2); s += __shfl_xor(s, 4);
  if (seg == 0) outp[row] = s + bias[0];
}

// logits head: N=16, x bf16, w staged bf16 in LDS. 16 rows/block, thread=(row,j).
__global__ __launch_bounds__(256) void logits_head_kernel(
    const unsigned short* __restrict__ x, const float* __restrict__ w,
    const float* __restrict__ bias, float* __restrict__ outp)
{
  __shared__ unsigned short xsh[16*520];
  __shared__ unsigned short wsh[16*520];
  const int tid = threadIdx.x;
  const int row0 = blockIdx.x*16;
  {
    const int r = tid >> 4, kc = (tid & 15)*32;
    const unsigned short* xr = x + (size_t)(row0 + r)*EE + kc;
    #pragma unroll
    for (int i = 0; i < 4; ++i)
      *(short8*)&xsh[r*520 + kc + i*8] = *(const short8*)(xr + i*8);
    const int j = r;
    #pragma unroll
    for (int kk = 0; kk < 32; ++kk)
      wsh[j*520 + kc + kk] = f2bs(w[(size_t)(kc + kk)*16 + j]);
  }
  __syncthreads();
  const int r = tid >> 4, j = tid & 15;
  float s = 0.f;
  for (int k = 0; k < EE; k += 8){
    short8 xv = *(const short8*)&xsh[r*520 + k];
    short8 wv = *(const short8*)&wsh[j*520 + k];
    #pragma unroll
    for (int e = 0; e < 8; ++e)
      s += bs2f((unsigned short)xv[e]) * bs2f((unsigned short)wv[e]);
  }
  outp[(size_t)(row0 + r)*16 + j] = s + bias[j];
}

// ---------------- orchestration ----------------
extern "C" void kernel_launch(void* const* d_in, const int* in_sizes, int n_in,
                              void* d_out, int out_size, void* d_ws, size_t ws_size,
                              hipStream_t stream)
{
  const float* obs     = (const float*)d_in[0];
  const float* action  = (const float*)d_in[1];
  const float* enc_hs  = (const float*)d_in[2];
  const float* dec_hs1 = (const float*)d_in[3];
  const float* dec_hs2 = (const float*)d_in[4];
  const int*   stepc   = (const int*)d_in[5];
  const float* eoln = (const float*)d_in[6];
  const float* eow  = (const float*)d_in[7];
  const float* eln  = (const float*)d_in[8];
  const float* ewq  = (const float*)d_in[9];
  const float* ewk  = (const float*)d_in[10];
  const float* ewv  = (const float*)d_in[11];
  const float* ewo  = (const float*)d_in[12];
  const float* eln1 = (const float*)d_in[13];
  const float* eln2 = (const float*)d_in[14];
  const float* efg  = (const float*)d_in[15];
  const float* efp  = (const float*)d_in[16];
  const float* ehw1 = (const float*)d_in[17];
  const float* ehb1 = (const float*)d_in[18];
  const float* ehln = (const float*)d_in[19];
  const float* ehw2 = (const float*)d_in[20];
  const float* ehb2 = (const float*)d_in[21];
  const float* daw  = (const float*)d_in[22];
  const float* dln  = (const float*)d_in[23];
  const float* dwq1 = (const float*)d_in[24];
  const float* dwk1 = (const float*)d_in[25];
  const float* dwv1 = (const float*)d_in[26];
  const float* dwo1 = (const float*)d_in[27];
  const float* dwq2 = (const float*)d_in[28];
  const float* dwk2 = (const float*)d_in[29];
  const float* dwv2 = (const float*)d_in[30];
  const float* dwo2 = (const float*)d_in[31];
  const float* dln1 = (const float*)d_in[32];
  const float* dln2 = (const float*)d_in[33];
  const float* dln3 = (const float*)d_in[34];
  const float* dfg  = (const float*)d_in[35];
  const float* dfp  = (const float*)d_in[36];
  const float* dhw1 = (const float*)d_in[37];
  const float* dhb1 = (const float*)d_in[38];
  const float* dhln = (const float*)d_in[39];
  const float* dhw2 = (const float*)d_in[40];
  const float* dhb2 = (const float*)d_in[41];

  const size_t BUF = (size_t)MM*EE;
  const size_t PART = (size_t)BB*HH*4*DH*DH;
  // fp32 region
  float* wsf  = (float*)d_ws;
  float* qb   = wsf;
  float* kb   = qb + BUF;
  float* vb   = kb + BUF;
  float* part = vb + BUF;
  float* tmx  = part + PART;
  // bf16 region
  unsigned short* ub = (unsigned short*)(tmx + 64);
  unsigned short* xrep_b    = ub;  ub += BUF;
  unsigned short* xrep_pe_b = ub;  ub += BUF;
  unsigned short* x_b       = ub;  ub += BUF;
  unsigned short* x_pe_b    = ub;  ub += BUF;
  unsigned short* t1_b      = ub;  ub += BUF;
  unsigned short* t1_pe_b   = ub;  ub += BUF;
  unsigned short* peb       = ub;  ub += BUF;
  unsigned short* obs_n     = ub;  ub += (size_t)MM*OBSD;
  unsigned short* act_b     = ub;  ub += (size_t)MM*64;
  // weights
  const size_t W55 = (size_t)EE*EE;
  unsigned short* wts = ub;  ub += 50*W55;
  unsigned short* wt_eow = ub; ub += (size_t)EE*OBSD;
  unsigned short* wt_daw = ub; ub += (size_t)EE*64;
  size_t need = (char*)ub - (char*)d_ws;
  if (ws_size < need) return;

  // weight slot map (50 x 512x512, in this order)
  unsigned short* wt_ewq  = wts + 0*W55;
  unsigned short* wt_ewk  = wts + 3*W55;
  unsigned short* wt_ewv  = wts + 6*W55;
  unsigned short* wt_ewo  = wts + 9*W55;
  unsigned short* wt_efg  = wts + 12*W55;
  unsigned short* wt_efp  = wts + 15*W55;
  unsigned short* wt_ehw1 = wts + 18*W55;
  unsigned short* wt_dwq1 = wts + 19*W55;
  unsigned short* wt_dwk1 = wts + 22*W55;
  unsigned short* wt_dwv1 = wts + 25*W55;
  unsigned short* wt_dwo1 = wts + 28*W55;
  unsigned short* wt_dwq2 = wts + 31*W55;
  unsigned short* wt_dwk2 = wts + 34*W55;
  unsigned short* wt_dwv2 = wts + 37*W55;
  unsigned short* wt_dwo2 = wts + 40*W55;
  unsigned short* wt_dfg  = wts + 43*W55;
  unsigned short* wt_dfp  = wts + 46*W55;
  unsigned short* wt_dhw1 = wts + 49*W55;

  float* out        = (float*)d_out;
  float* value_out  = out;
  float* logits_out = out + 8192;
  float* enc_out    = logits_out + (size_t)MM*16;
  float* d1_out     = enc_out + (size_t)BB*LL*HH*DH*DH;
  float* d2_out     = d1_out  + (size_t)BB*LL*HH*DH*DH;

  const size_t HS_L = (size_t)HH*DH*DH;

  // batched transpose of all 50 square weights
  {
    TP50 tp;
    const float* srcs[18] = {ewq, ewk, ewv, ewo, efg, efp, ehw1,
                             dwq1, dwk1, dwv1, dwo1, dwq2, dwk2, dwv2, dwo2, dfg, dfp, dhw1};
    const int cnt[18] = {3,3,3,3,3,3,1, 3,3,3,3,3,3,3,3,3,3,1};
    int z = 0;
    for (int i = 0; i < 18; ++i)
      for (int j = 0; j < cnt[i]; ++j){
        tp.s[z] = srcs[i] + (size_t)j*W55;
        tp.d[z] = wts + (size_t)z*W55;
        ++z;
      }
    wtpose_batch_kernel<<<dim3(16,16,50), dim3(32,8), 0, stream>>>(tp);
  }
  wtpose_kernel<<<dim3(4,16), dim3(32,8), 0, stream>>>(eow, wt_eow, OBSD, OBSD);
  wtpose_kernel<<<dim3(2,16), dim3(32,8), 0, stream>>>(daw, wt_daw, ACTD, 64);

  pe_kernel<<<(MM*EE)/256, 256, 0, stream>>>(stepc, peb);
  tsmax_kernel<<<BB, 256, 0, stream>>>(stepc, tmx);

  auto gemm = [&](const unsigned short* A, const unsigned short* Wt, const float* bias,
                  float* C, int Kpad, float scale, int act){
    gemm_b_kernel<<<dim3(EE/64, MM/128), 256, 0, stream>>>(A, Wt, bias, C, Kpad, scale, act);
  };
  auto norm = [&](const float* af, const unsigned short* ab, const float* res,
                  const float* g, const float* p, const float* w,
                  unsigned short* o1, unsigned short* o2, int mode){
    norm_b_kernel<<<MM, 256, 0, stream>>>(af, ab, res, g, p, w, o1, o2, peb, mode);
  };
  auto retention = [&](const float* qp, const float* kp, const float* vp,
                       const float* h0, unsigned short* o, int masked){
    retention_kernel<<<dim3(4, HH, BB), 256, 0, stream>>>(qp, kp, vp, h0, stepc, o, masked);
  };
  auto hstate = [&](const float* h0, float* o){
    hstate_partial_kernel<<<dim3(4,HH,BB), 256, 0, stream>>>(kb, vb, stepc, tmx, part);
    hstate_final_kernel<<<2048, 256, 0, stream>>>(part, h0, tmx, o);
  };

  // ---- encoder embed ----
  norm_obs_kernel<<<MM, 128, 0, stream>>>(obs, eoln, obs_n);
  // obs_rep fp32 not needed: gemm writes fp32 qb then? -> write obs_rep via gemm into qb, then norm? No:
  // obs_rep = gelu(norm(obs)@eow) is a residual-stream value consumed by eln (norm). Route: gemm -> qb (fp32), eln reads fp32.
  gemm(obs_n, wt_eow, nullptr, qb, OBSD, 1.f, ACT_GELU);   // qb = obs_rep (fp32)

  // ---- encoder layers ----
  // xrep lives as: first iteration fp32 in qb; afterwards bf16 in xrep_b
  for (int i = 0; i < LL; ++i){
    if (i == 0) norm(qb, nullptr, nullptr, nullptr, nullptr, eln, x_b, x_pe_b, NORM_PLAIN);
    else        norm(nullptr, xrep_b, nullptr, nullptr, nullptr, eln, x_b, x_pe_b, NORM_PLAIN);
    gemm(x_pe_b, wt_ewq + i*W55, nullptr, qb, EE, 1.f, ACT_NONE);
    gemm(x_pe_b, wt_ewk + i*W55, nullptr, kb, EE, INV_SQRT_D, ACT_NONE);
    gemm(x_pe_b, wt_ewv + i*W55, nullptr, vb, EE, 1.f, ACT_NONE);
    retention(qb, kb, vb, enc_hs + i*HS_L, t1_b, 0);
    hstate(enc_hs + i*HS_L, enc_out + i*HS_L);
    gemm(t1_b, wt_ewo + i*W55, nullptr, vb, EE, 1.f, ACT_NONE);
    norm(nullptr, x_b, vb, nullptr, nullptr, eln1 + i*EE, t1_b, nullptr, NORM_ADD);
    gemm(t1_b, wt_efg + i*W55, nullptr, qb, EE, 1.f, ACT_NONE);
    gemm(t1_b, wt_efp + i*W55, nullptr, kb, EE, 1.f, ACT_NONE);
    norm(nullptr, t1_b, nullptr, qb, kb, eln2 + i*EE, xrep_b, xrep_pe_b, NORM_SWIGLU);
  }

  // ---- value head ----
  gemm(xrep_b, wt_ehw1, ehb1, qb, EE, 1.f, ACT_GELU);
  norm(qb, nullptr, nullptr, nullptr, nullptr, ehln, t1_b, nullptr, NORM_PLAIN);
  value_head_kernel<<<MM/32, 256, 0, stream>>>(t1_b, ehw2, ehb2, value_out);

  // ---- decoder embed ----
  act_embed_kernel<<<(MM*64)/256, 256, 0, stream>>>(action, act_b);
  gemm(act_b, wt_daw, nullptr, qb, 64, 1.f, ACT_GELU);
  norm(qb, nullptr, nullptr, nullptr, nullptr, dln, x_b, x_pe_b, NORM_PLAIN);

  // ---- decoder layers ----
  for (int i = 0; i < LL; ++i){
    gemm(x_pe_b, wt_dwq1 + i*W55, nullptr, qb, EE, 1.f, ACT_NONE);
    gemm(x_pe_b, wt_dwk1 + i*W55, nullptr, kb, EE, INV_SQRT_D, ACT_NONE);
    gemm(x_pe_b, wt_dwv1 + i*W55, nullptr, vb, EE, 1.f, ACT_NONE);
    retention(qb, kb, vb, dec_hs1 + i*HS_L, t1_b, 1);
    hstate(dec_hs1 + i*HS_L, d1_out + i*HS_L);
    gemm(t1_b, wt_dwo1 + i*W55, nullptr, vb, EE, 1.f, ACT_NONE);
    norm(nullptr, x_b, vb, nullptr, nullptr, dln1 + i*EE, t1_b, t1_pe_b, NORM_ADD);   // r
    gemm(xrep_pe_b, wt_dwq2 + i*W55, nullptr, qb, EE, 1.f, ACT_NONE);
    gemm(t1_pe_b,   wt_dwk2 + i*W55, nullptr, kb, EE, INV_SQRT_D, ACT_NONE);
    gemm(t1_pe_b,   wt_dwv2 + i*W55, nullptr, vb, EE, 1.f, ACT_NONE);
    retention(qb, kb, vb, dec_hs2 + i*HS_L, t1_b, 1);
    hstate(dec_hs2 + i*HS_L, d2_out + i*HS_L);
    gemm(t1_b, wt_dwo2 + i*W55, nullptr, vb, EE, 1.f, ACT_NONE);
    norm(nullptr, xrep_b, vb, nullptr, nullptr, dln2 + i*EE, x_b, nullptr, NORM_ADD); // y
    gemm(x_b, wt_dfg + i*W55, nullptr, qb, EE, 1.f, ACT_NONE);
    gemm(x_b, wt_dfp + i*W55, nullptr, kb, EE, 1.f, ACT_NONE);
    norm(nullptr, x_b, nullptr, qb, kb, dln3 + i*EE, x_b, x_pe_b, NORM_SWIGLU);
  }

  // ---- logits head ----
  gemm(x_b, wt_dhw1, dhb1, qb, EE, 1.f, ACT_GELU);
  norm(qb, nullptr, nullptr, nullptr, nullptr, dhln, t1_b, nullptr, NORM_PLAIN);
  logits_head_kernel<<<MM/16, 256, 0, stream>>>(t1_b, dhw2, dhb2, logits_out);
}

// Round 8
// 1786.743 us; speedup vs baseline: 26.5803x; 1.0027x over previous
//
#include <hip/hip_runtime.h>
#include <hip/hip_bf16.h>
#include <math.h>

typedef __attribute__((ext_vector_type(8))) short short8;     // 8 bf16 = 4 VGPRs
typedef __attribute__((ext_vector_type(4))) short short4v;    // 4 bf16 = 8B
typedef __attribute__((ext_vector_type(4))) float f32x4;

#define BB 16
#define SS 512
#define EE 512
#define HH 8
#define DH 64
#define LL 3
#define MM (BB*SS)
#define OBSD 128
#define ACTD 17
#define INV_SQRT_D 0.125f

#define ACT_NONE 0
#define ACT_GELU 1

#define NORM_PLAIN 0
#define NORM_ADD 1
#define NORM_SWIGLU 2

__device__ __forceinline__ float gelu_f(float x){
  float x3 = x*x*x;
  return 0.5f*x*(1.f + tanhf(0.7978845608028654f*(x + 0.044715f*x3)));
}
__device__ __forceinline__ float silu_f(float x){ return x/(1.f+expf(-x)); }
__device__ __forceinline__ float lkappa(int h){ return logf(1.f - exp2f(-5.f - (float)h)); }
__device__ __forceinline__ unsigned short f2bs(float f){
  unsigned int u = __float_as_uint(f);
  u += 0x7FFFu + ((u >> 16) & 1u);
  return (unsigned short)(u >> 16);
}
__device__ __forceinline__ float bs2f(unsigned short u){
  return __uint_as_float(((unsigned int)u) << 16);
}

// ---------------- weight transpose: W[K][512] fp32 -> Wt[512][Kpad] bf16 ----------------
__global__ __launch_bounds__(256) void wtpose_kernel(
    const float* __restrict__ src, unsigned short* __restrict__ dst, int K, int Kpad)
{
  __shared__ float t[32][33];
  const int gx = blockIdx.x, gy = blockIdx.y;
  const int tx = threadIdx.x, ty = threadIdx.y;
  #pragma unroll
  for (int i = 0; i < 4; ++i){
    int k = gx*32 + ty + i*8, n = gy*32 + tx;
    t[ty+i*8][tx] = (k < K) ? src[(size_t)k*EE + n] : 0.f;
  }
  __syncthreads();
  #pragma unroll
  for (int i = 0; i < 4; ++i){
    int k = gx*32 + tx, n = gy*32 + ty + i*8;
    dst[(size_t)n*Kpad + k] = f2bs(t[tx][ty+i*8]);
  }
}

struct TP50 { const float* s[50]; unsigned short* d[50]; };
__global__ __launch_bounds__(256) void wtpose_batch_kernel(TP50 tp)
{
  __shared__ float t[32][33];
  const float* src = tp.s[blockIdx.z];
  unsigned short* dst = tp.d[blockIdx.z];
  const int gx = blockIdx.x, gy = blockIdx.y;
  const int tx = threadIdx.x, ty = threadIdx.y;
  #pragma unroll
  for (int i = 0; i < 4; ++i){
    int k = gx*32 + ty + i*8, n = gy*32 + tx;
    t[ty+i*8][tx] = src[(size_t)k*EE + n];
  }
  __syncthreads();
  #pragma unroll
  for (int i = 0; i < 4; ++i){
    int k = gx*32 + tx, n = gy*32 + ty + i*8;
    dst[(size_t)n*EE + k] = f2bs(t[tx][ty+i*8]);
  }
}

// ---------------- MFMA GEMM: act(scale*(A_b@W) + bias) -> fp32 C and/or bf16 Cb and/or per-head CT ----------------
__global__ __launch_bounds__(256) void gemm_b_kernel(
    const unsigned short* __restrict__ A, const unsigned short* __restrict__ Wt,
    const float* __restrict__ bias, float* __restrict__ C,
    unsigned short* __restrict__ Cb, unsigned short* __restrict__ CT,
    int Kpad, float scale, int act)
{
  __shared__ unsigned short As[128*72];
  __shared__ unsigned short Bs[64*72];
  const int bm = blockIdx.y*128, bn = blockIdx.x*64;
  const int tid = threadIdx.x, lane = tid & 63, wv = tid >> 6;
  const int wr = wv >> 1, wc = wv & 1;
  const int l16 = lane & 15, quad = lane >> 4;

  f32x4 acc[4][2];
  #pragma unroll
  for (int i=0;i<4;i++){ acc[i][0]=(f32x4)(0.f); acc[i][1]=(f32x4)(0.f); }

  const int arow = tid >> 1, acol = (tid & 1)*32;
  const int brow = tid >> 2, bcol = (tid & 3)*16;

  for (int k0 = 0; k0 < Kpad; k0 += 64){
    const unsigned short* ag = A + (size_t)(bm+arow)*Kpad + k0 + acol;
    #pragma unroll
    for (int i=0;i<4;i++)
      *(short8*)&As[arow*72 + acol + i*8] = *(const short8*)(ag + i*8);
    const unsigned short* bg = Wt + (size_t)(bn+brow)*Kpad + k0 + bcol;
    #pragma unroll
    for (int i=0;i<2;i++)
      *(short8*)&Bs[brow*72 + bcol + i*8] = *(const short8*)(bg + i*8);
    __syncthreads();
    short8 af[4][2], bf[2][2];
    #pragma unroll
    for (int mt=0; mt<4; ++mt)
      #pragma unroll
      for (int ks=0; ks<2; ++ks)
        af[mt][ks] = *(const short8*)&As[(wr*64 + mt*16 + l16)*72 + ks*32 + quad*8];
    #pragma unroll
    for (int nt=0; nt<2; ++nt)
      #pragma unroll
      for (int ks=0; ks<2; ++ks)
        bf[nt][ks] = *(const short8*)&Bs[(wc*32 + nt*16 + l16)*72 + ks*32 + quad*8];
    #pragma unroll
    for (int ks=0; ks<2; ++ks)
      #pragma unroll
      for (int mt=0; mt<4; ++mt)
        #pragma unroll
        for (int nt=0; nt<2; ++nt)
          acc[mt][nt] = __builtin_amdgcn_mfma_f32_16x16x32_bf16(af[mt][ks], bf[nt][ks], acc[mt][nt], 0, 0, 0);
    __syncthreads();
  }
  #pragma unroll
  for (int mt=0; mt<4; ++mt){
    #pragma unroll
    for (int nt=0; nt<2; ++nt){
      int col = bn + wc*32 + nt*16 + l16;
      float bv = bias ? bias[col] : 0.f;
      int rb = bm + wr*64 + mt*16 + quad*4;
      float vals[4];
      #pragma unroll
      for (int j=0;j<4;j++){
        float v = acc[mt][nt][j]*scale + bv;
        if (act==ACT_GELU) v = gelu_f(v);
        vals[j] = v;
      }
      if (C){
        #pragma unroll
        for (int j=0;j<4;j++) C[(size_t)(rb+j)*EE + col] = vals[j];
      }
      if (Cb){
        #pragma unroll
        for (int j=0;j<4;j++) Cb[(size_t)(rb+j)*EE + col] = f2bs(vals[j]);
      }
      if (CT){
        int bloc = rb >> 9, m0 = rb & 511;
        int hh = col >> 6, ee = col & 63;
        short4v pk;
        #pragma unroll
        for (int j=0;j<4;j++) pk[j] = (short)f2bs(vals[j]);
        *(short4v*)&CT[(((size_t)bloc*HH + hh)*DH + ee)*SS + m0] = pk;
      }
    }
  }
}

// ---------------- rmsnorm: mixed fp32/bf16 input -> bf16 out (+ optional out+pe) ----------------
__global__ __launch_bounds__(256) void norm_b_kernel(
    const float* __restrict__ af, const unsigned short* __restrict__ ab,
    const float* __restrict__ res, const float* __restrict__ g, const float* __restrict__ p,
    const float* __restrict__ w, unsigned short* __restrict__ o1,
    unsigned short* __restrict__ o2, const unsigned short* __restrict__ peb,
    int mode)
{
  __shared__ float red[4];
  const int row = blockIdx.x, tid = threadIdx.x;
  const size_t base = (size_t)row*EE + tid*2;
  float t0, t1;
  if (ab){
    unsigned int av = *(const unsigned int*)&ab[base];
    t0 = bs2f((unsigned short)(av & 0xffffu));
    t1 = bs2f((unsigned short)(av >> 16));
  } else {
    float2 av = *(const float2*)&af[base];
    t0 = av.x; t1 = av.y;
  }
  if (mode == NORM_ADD){
    float2 rv = *(const float2*)&res[base];
    t0 += rv.x; t1 += rv.y;
  } else if (mode == NORM_SWIGLU){
    float2 gv = *(const float2*)&g[base];
    float2 pv = *(const float2*)&p[base];
    t0 += silu_f(gv.x)*pv.x; t1 += silu_f(gv.y)*pv.y;
  }
  float ss = t0*t0 + t1*t1;
  #pragma unroll
  for (int o=32;o;o>>=1) ss += __shfl_down(ss,o);
  if ((tid&63)==0) red[tid>>6]=ss;
  __syncthreads();
  if (tid==0) red[0] = 1.f/sqrtf((red[0]+red[1]+red[2]+red[3])/(float)EE + 1e-6f);
  __syncthreads();
  float r = red[0];
  float2 wv2 = *(const float2*)&w[tid*2];
  float y0 = t0*r*wv2.x, y1 = t1*r*wv2.y;
  unsigned int pk = (unsigned int)f2bs(y0) | ((unsigned int)f2bs(y1) << 16);
  *(unsigned int*)&o1[base] = pk;
  if (o2){
    unsigned int pv = *(const unsigned int*)&peb[base];
    float z0 = y0 + bs2f((unsigned short)(pv & 0xffffu));
    float z1 = y1 + bs2f((unsigned short)(pv >> 16));
    *(unsigned int*)&o2[base] = (unsigned int)f2bs(z0) | ((unsigned int)f2bs(z1) << 16);
  }
}

// obs norm: fp32 [MM][128] -> bf16
__global__ __launch_bounds__(128) void norm_obs_kernel(
    const float* __restrict__ a, const float* __restrict__ w, unsigned short* __restrict__ o)
{
  __shared__ float red[2];
  const int row = blockIdx.x, tid = threadIdx.x;
  float t = a[(size_t)row*OBSD + tid];
  float ss = t*t;
  #pragma unroll
  for (int off=32;off;off>>=1) ss += __shfl_down(ss,off);
  if ((tid&63)==0) red[tid>>6]=ss;
  __syncthreads();
  if (tid==0) red[0] = 1.f/sqrtf((red[0]+red[1])/(float)OBSD + 1e-6f);
  __syncthreads();
  o[(size_t)row*OBSD + tid] = f2bs(t*red[0]*w[tid]);
}

// action embed: fp32 [MM][17] -> bf16 [MM][64] zero-padded
__global__ __launch_bounds__(256) void act_embed_kernel(
    const float* __restrict__ a, unsigned short* __restrict__ o)
{
  int idx = blockIdx.x*256 + threadIdx.x;
  int row = idx >> 6, col = idx & 63;
  o[idx] = (col < ACTD) ? f2bs(a[(size_t)row*ACTD + col]) : 0;
}

// ---------------- MFMA retention: bf16 q,k normal; v transposed per head ----------------
__global__ __launch_bounds__(256) void retention_kernel(
    const unsigned short* __restrict__ q, const unsigned short* __restrict__ k,
    const unsigned short* __restrict__ vT,
    const float* __restrict__ h0, const int* __restrict__ tsi,
    unsigned short* __restrict__ outp, int masked)
{
  __shared__ unsigned short qsh[128*72];
  __shared__ unsigned short ksh[64*72];
  __shared__ unsigned short vsh[64*72];   // [e][m_local]
  __shared__ unsigned short psh[128*72];
  __shared__ float tsf[SS];
  const int b = blockIdx.z, h = blockIdx.y;
  const int n0 = blockIdx.x * 128;
  const int tid = threadIdx.x, lane = tid & 63, wv = tid >> 6;
  const int quad = lane >> 4, l16 = lane & 15;
  const float lk = lkappa(h);

  for (int i = tid; i < SS; i += 256) tsf[i] = (float)tsi[b*SS + i];
  {
    const int n = tid >> 1, half = (tid & 1) * 32;
    const unsigned short* qr = q + ((size_t)b*SS + n0 + n)*EE + h*DH + half;
    #pragma unroll
    for (int i = 0; i < 4; ++i)
      *(short8*)&qsh[n*72 + half + i*8] = *(const short8*)(qr + i*8);
  }
  {
    const float* h0b = h0 + (size_t)b*(LL*HH*DH*DH) + (size_t)h*(DH*DH);
    const int d = tid >> 2, eb = (tid & 3) * 16;
    #pragma unroll
    for (int i = 0; i < 4; ++i){
      float4 f = *(const float4*)(h0b + d*DH + eb + i*4);
      ksh[(eb+i*4+0)*72 + d] = f2bs(f.x);
      ksh[(eb+i*4+1)*72 + d] = f2bs(f.y);
      ksh[(eb+i*4+2)*72 + d] = f2bs(f.z);
      ksh[(eb+i*4+3)*72 + d] = f2bs(f.w);
    }
  }
  __syncthreads();

  float maxn = fmaxf(tsf[n0 + lane], tsf[n0 + 64 + lane]);
  #pragma unroll
  for (int o=32;o;o>>=1) maxn = fmaxf(maxn, __shfl_xor(maxn, o));

  const int rowbase = wv*32;
  short8 qa[2][2];
  #pragma unroll
  for (int rt=0; rt<2; ++rt)
    #pragma unroll
    for (int ks=0; ks<2; ++ks)
      qa[rt][ks] = *(const short8*)&qsh[(rowbase + rt*16 + l16)*72 + ks*32 + quad*8];

  f32x4 acc_o[2][4];
  #pragma unroll
  for (int rt=0; rt<2; ++rt){
    #pragma unroll
    for (int et=0; et<4; ++et){
      f32x4 a = (f32x4)(0.f);
      #pragma unroll
      for (int ks=0; ks<2; ++ks){
        short8 hb = *(const short8*)&ksh[(et*16 + l16)*72 + ks*32 + quad*8];
        a = __builtin_amdgcn_mfma_f32_16x16x32_bf16(qa[rt][ks], hb, a, 0, 0, 0);
      }
      acc_o[rt][et] = a;
    }
  }
  #pragma unroll
  for (int rt=0; rt<2; ++rt){
    #pragma unroll
    for (int j=0;j<4;j++){
      float xi = __expf(lk*(tsf[n0 + rowbase + rt*16 + quad*4 + j] + 1.f));
      #pragma unroll
      for (int et=0; et<4; ++et) acc_o[rt][et][j] *= xi;
    }
  }

  for (int mc = 0; mc < SS; mc += 64){
    if (masked){
      float mn = tsf[mc + lane];
      #pragma unroll
      for (int o=32;o;o>>=1) mn = fminf(mn, __shfl_xor(mn, o));
      if (mn > maxn) continue;
    }
    __syncthreads();
    {
      const int m = tid >> 2, cb = (tid & 3) * 16;
      const unsigned short* krow = k + ((size_t)b*SS + mc + m)*EE + h*DH + cb;
      #pragma unroll
      for (int i = 0; i < 2; ++i)
        *(short8*)&ksh[m*72 + cb + i*8] = *(const short8*)(krow + i*8);
      const int e = tid >> 2, mseg = (tid & 3) * 16;
      const unsigned short* vrow = vT + (((size_t)b*HH + h)*DH + e)*SS + mc + mseg;
      #pragma unroll
      for (int i = 0; i < 2; ++i)
        *(short8*)&vsh[e*72 + mseg + i*8] = *(const short8*)(vrow + i*8);
    }
    __syncthreads();
    f32x4 sacc[2][4];
    #pragma unroll
    for (int rt=0; rt<2; ++rt)
      #pragma unroll
      for (int mt=0; mt<4; ++mt){
        f32x4 a = (f32x4)(0.f);
        #pragma unroll
        for (int ks=0; ks<2; ++ks){
          short8 kb = *(const short8*)&ksh[(mt*16 + l16)*72 + ks*32 + quad*8];
          a = __builtin_amdgcn_mfma_f32_16x16x32_bf16(qa[rt][ks], kb, a, 0, 0, 0);
        }
        sacc[rt][mt] = a;
      }
    float tsm[4]; int mg[4];
    #pragma unroll
    for (int mt=0; mt<4; ++mt){ mg[mt] = mc + mt*16 + l16; tsm[mt] = tsf[mg[mt]]; }
    #pragma unroll
    for (int rt=0; rt<2; ++rt){
      #pragma unroll
      for (int j=0;j<4;j++){
        int nloc = rowbase + rt*16 + quad*4 + j;
        int n = n0 + nloc;
        float tsn = tsf[n];
        #pragma unroll
        for (int mt=0; mt<4; ++mt){
          float diff = tsn - tsm[mt];
          float wgt;
          if (masked) wgt = ((diff > 0.f) || (diff == 0.f && n >= mg[mt])) ? __expf(lk*diff) : 0.f;
          else        wgt = __expf(lk*fabsf(diff));
          psh[nloc*72 + mt*16 + l16] = f2bs(sacc[rt][mt][j]*wgt);
        }
      }
    }
    #pragma unroll
    for (int rt=0; rt<2; ++rt){
      #pragma unroll
      for (int ks=0; ks<2; ++ks){
        short8 pa = *(const short8*)&psh[(rowbase + rt*16 + l16)*72 + ks*32 + quad*8];
        #pragma unroll
        for (int et=0; et<4; ++et){
          short8 vb = *(const short8*)&vsh[(et*16 + l16)*72 + ks*32 + quad*8];
          acc_o[rt][et] = __builtin_amdgcn_mfma_f32_16x16x32_bf16(pa, vb, acc_o[rt][et], 0, 0, 0);
        }
      }
    }
  }
  #pragma unroll
  for (int rt=0; rt<2; ++rt){
    #pragma unroll
    for (int j=0;j<4;j++){
      size_t rbase = ((size_t)b*SS + n0 + rowbase + rt*16 + quad*4 + j)*EE + h*DH;
      #pragma unroll
      for (int et=0; et<4; ++et)
        outp[rbase + et*16 + l16] = f2bs(acc_o[rt][et][j]);
    }
  }
}

// ---------------- recurrent state (bf16 k,v in; fp32 math) ----------------
__global__ __launch_bounds__(256) void hstate_partial_kernel(
    const unsigned short* __restrict__ k, const unsigned short* __restrict__ v,
    const int* __restrict__ tsi, const float* __restrict__ tmx,
    float* __restrict__ part)
{
  __shared__ float ksh[64*68];
  __shared__ float vsh[64*64];
  __shared__ float wsh[64];
  const int qr = blockIdx.x, h = blockIdx.y, b = blockIdx.z;
  const int tid = threadIdx.x, lane = tid & 63, wv = tid >> 6;
  const float lk = lkappa(h);
  const float tm = tmx[b];
  float acc[16];
  #pragma unroll
  for (int i=0;i<16;i++) acc[i]=0.f;
  for (int mc = qr*256; mc < qr*256 + 256; mc += 64){
    {
      const int m = tid >> 2, seg = (tid & 3) * 16;
      const unsigned short* krow = k + ((size_t)b*SS + mc + m)*EE + h*DH + seg;
      const unsigned short* vrow = v + ((size_t)b*SS + mc + m)*EE + h*DH + seg;
      #pragma unroll
      for (int i = 0; i < 2; ++i){
        short8 kv = *(const short8*)(krow + i*8);
        short8 vv = *(const short8*)(vrow + i*8);
        #pragma unroll
        for (int e = 0; e < 8; ++e){
          ksh[m*68 + seg + i*8 + e] = bs2f((unsigned short)kv[e]);
          vsh[m*64 + seg + i*8 + e] = bs2f((unsigned short)vv[e]);
        }
      }
    }
    if (tid < 64) wsh[tid] = expf(lk*(tm - (float)tsi[b*SS + mc + tid]));
    __syncthreads();
    for (int m = 0; m < 64; ++m){
      float wvv = wsh[m]*vsh[m*64 + lane];
      const float* kr = &ksh[m*68 + wv*16];
      #pragma unroll
      for (int i = 0; i < 16; i += 4){
        float4 k4 = *(const float4*)&kr[i];
        acc[i+0] += k4.x*wvv; acc[i+1] += k4.y*wvv;
        acc[i+2] += k4.z*wvv; acc[i+3] += k4.w*wvv;
      }
    }
    __syncthreads();
  }
  float* pp = part + ((((size_t)b*HH + h)*2 + qr)*DH + wv*16)*DH + lane;
  #pragma unroll
  for (int i=0;i<16;i++) pp[(size_t)i*DH] = acc[i];
}

__global__ __launch_bounds__(256) void hstate_final_kernel(
    const float* __restrict__ part, const float* __restrict__ h0,
    const float* __restrict__ tmx, float* __restrict__ outp)
{
  int idx = blockIdx.x*256 + threadIdx.x;
  int e = idx & 63, d = (idx>>6) & 63, h = (idx>>12) & 7, b = idx >> 15;
  float lk = lkappa(h);
  float dec = expf(lk*(tmx[b] + 1.f));
  const float* pp = part + (((size_t)b*HH + h)*2*DH + d)*DH + e;
  float s = pp[0] + pp[DH*DH];
  size_t off = (size_t)b*(LL*HH*DH*DH) + (size_t)h*DH*DH + d*DH + e;
  outp[off] = dec*h0[off] + s;
}

// ---------------- small helpers ----------------
__global__ void tsmax_kernel(const int* __restrict__ tsi, float* __restrict__ tmx){
  __shared__ int red[4];
  int b = blockIdx.x, tid = threadIdx.x;
  int m = max(tsi[b*SS+tid], tsi[b*SS+256+tid]);
  #pragma unroll
  for (int o=32;o;o>>=1) m = max(m, __shfl_down(m,o));
  if ((tid&63)==0) red[tid>>6]=m;
  __syncthreads();
  if (tid==0) tmx[b] = (float)max(max(red[0],red[1]),max(red[2],red[3]));
}

__global__ void pe_kernel(const int* __restrict__ tsi, unsigned short* __restrict__ peb){
  int idx = blockIdx.x*256 + threadIdx.x;
  int row = idx >> 9, j = idx & 511;
  float ts = (float)tsi[row];
  int jj = j & 255;
  float freq = expf(-9.210340371976184f*(float)jj*(1.f/256.f));
  float ang = ts*freq;
  peb[idx] = f2bs((j < 256) ? sinf(ang) : cosf(ang));
}

__global__ __launch_bounds__(256) void value_head_kernel(
    const unsigned short* __restrict__ x, const float* __restrict__ w,
    const float* __restrict__ bias, float* __restrict__ outp)
{
  const int tid = threadIdx.x, lane = tid & 63, wv = tid >> 6;
  const int r8 = lane >> 3, seg = lane & 7;
  const int row = blockIdx.x*32 + wv*8 + r8;
  const unsigned short* xr = x + (size_t)row*EE + seg*64;
  const float* wr = w + seg*64;
  float s = 0.f;
  #pragma unroll
  for (int i = 0; i < 8; ++i){
    short8 xv = *(const short8*)(xr + i*8);
    #pragma unroll
    for (int e = 0; e < 8; ++e)
      s += bs2f((unsigned short)xv[e]) * wr[i*8 + e];
  }
  s += __shfl_xor(s, 1); s += __shfl_xor(s, 2); s += __shfl_xor(s, 4);
  if (seg == 0) outp[row] = s + bias[0];
}

__global__ __launch_bounds__(256) void logits_head_kernel(
    const unsigned short* __restrict__ x, const float* __restrict__ w,
    const float* __restrict__ bias, float* __restrict__ outp)
{
  __shared__ unsigned short xsh[16*520];
  __shared__ unsigned short wsh[16*520];
  const int tid = threadIdx.x;
  const int row0 = blockIdx.x*16;
  {
    const int r = tid >> 4, kc = (tid & 15)*32;
    const unsigned short* xr = x + (size_t)(row0 + r)*EE + kc;
    #pragma unroll
    for (int i = 0; i < 4; ++i)
      *(short8*)&xsh[r*520 + kc + i*8] = *(const short8*)(xr + i*8);
    const int j = r;
    #pragma unroll
    for (int kk = 0; kk < 32; ++kk)
      wsh[j*520 + kc + kk] = f2bs(w[(size_t)(kc + kk)*16 + j]);
  }
  __syncthreads();
  const int r = tid >> 4, j = tid & 15;
  float s = 0.f;
  for (int k = 0; k < EE; k += 8){
    short8 xv = *(const short8*)&xsh[r*520 + k];
    short8 wv = *(const short8*)&wsh[j*520 + k];
    #pragma unroll
    for (int e = 0; e < 8; ++e)
      s += bs2f((unsigned short)xv[e]) * bs2f((unsigned short)wv[e]);
  }
  outp[(size_t)(row0 + r)*16 + j] = s + bias[j];
}

// ---------------- orchestration ----------------
extern "C" void kernel_launch(void* const* d_in, const int* in_sizes, int n_in,
                              void* d_out, int out_size, void* d_ws, size_t ws_size,
                              hipStream_t stream)
{
  const float* obs     = (const float*)d_in[0];
  const float* action  = (const float*)d_in[1];
  const float* enc_hs  = (const float*)d_in[2];
  const float* dec_hs1 = (const float*)d_in[3];
  const float* dec_hs2 = (const float*)d_in[4];
  const int*   stepc   = (const int*)d_in[5];
  const float* eoln = (const float*)d_in[6];
  const float* eow  = (const float*)d_in[7];
  const float* eln  = (const float*)d_in[8];
  const float* ewq  = (const float*)d_in[9];
  const float* ewk  = (const float*)d_in[10];
  const float* ewv  = (const float*)d_in[11];
  const float* ewo  = (const float*)d_in[12];
  const float* eln1 = (const float*)d_in[13];
  const float* eln2 = (const float*)d_in[14];
  const float* efg  = (const float*)d_in[15];
  const float* efp  = (const float*)d_in[16];
  const float* ehw1 = (const float*)d_in[17];
  const float* ehb1 = (const float*)d_in[18];
  const float* ehln = (const float*)d_in[19];
  const float* ehw2 = (const float*)d_in[20];
  const float* ehb2 = (const float*)d_in[21];
  const float* daw  = (const float*)d_in[22];
  const float* dln  = (const float*)d_in[23];
  const float* dwq1 = (const float*)d_in[24];
  const float* dwk1 = (const float*)d_in[25];
  const float* dwv1 = (const float*)d_in[26];
  const float* dwo1 = (const float*)d_in[27];
  const float* dwq2 = (const float*)d_in[28];
  const float* dwk2 = (const float*)d_in[29];
  const float* dwv2 = (const float*)d_in[30];
  const float* dwo2 = (const float*)d_in[31];
  const float* dln1 = (const float*)d_in[32];
  const float* dln2 = (const float*)d_in[33];
  const float* dln3 = (const float*)d_in[34];
  const float* dfg  = (const float*)d_in[35];
  const float* dfp  = (const float*)d_in[36];
  const float* dhw1 = (const float*)d_in[37];
  const float* dhb1 = (const float*)d_in[38];
  const float* dhln = (const float*)d_in[39];
  const float* dhw2 = (const float*)d_in[40];
  const float* dhb2 = (const float*)d_in[41];

  const size_t BUF = (size_t)MM*EE;
  const size_t PART = (size_t)BB*HH*2*DH*DH;   // 2 m-halves
  // fp32 region
  float* wsf  = (float*)d_ws;
  float* f32a = wsf;              // wo-out / gate / gelu head / obs_rep
  float* f32b = f32a + BUF;       // proj
  float* part = f32b + BUF;
  float* tmx  = part + PART;
  // bf16 region
  unsigned short* ub = (unsigned short*)(tmx + 64);
  unsigned short* xrep_b    = ub;  ub += BUF;
  unsigned short* xrep_pe_b = ub;  ub += BUF;
  unsigned short* x_b       = ub;  ub += BUF;
  unsigned short* x_pe_b    = ub;  ub += BUF;
  unsigned short* t1_b      = ub;  ub += BUF;
  unsigned short* t1_pe_b   = ub;  ub += BUF;
  unsigned short* peb       = ub;  ub += BUF;
  unsigned short* q_b       = ub;  ub += BUF;
  unsigned short* k_b       = ub;  ub += BUF;
  unsigned short* v_b       = ub;  ub += BUF;
  unsigned short* vT_b      = ub;  ub += BUF;   // [B][H][64][512]
  unsigned short* obs_n     = ub;  ub += (size_t)MM*OBSD;
  unsigned short* act_b     = obs_n;            // aliased (obs_n dead by decoder embed)
  // weights
  const size_t W55 = (size_t)EE*EE;
  unsigned short* wts = ub;  ub += 50*W55;
  unsigned short* wt_eow = ub; ub += (size_t)EE*OBSD;
  unsigned short* wt_daw = ub; ub += (size_t)EE*64;
  size_t need = (char*)ub - (char*)d_ws;
  if (ws_size < need) return;

  unsigned short* wt_ewq  = wts + 0*W55;
  unsigned short* wt_ewk  = wts + 3*W55;
  unsigned short* wt_ewv  = wts + 6*W55;
  unsigned short* wt_ewo  = wts + 9*W55;
  unsigned short* wt_efg  = wts + 12*W55;
  unsigned short* wt_efp  = wts + 15*W55;
  unsigned short* wt_ehw1 = wts + 18*W55;
  unsigned short* wt_dwq1 = wts + 19*W55;
  unsigned short* wt_dwk1 = wts + 22*W55;
  unsigned short* wt_dwv1 = wts + 25*W55;
  unsigned short* wt_dwo1 = wts + 28*W55;
  unsigned short* wt_dwq2 = wts + 31*W55;
  unsigned short* wt_dwk2 = wts + 34*W55;
  unsigned short* wt_dwv2 = wts + 37*W55;
  unsigned short* wt_dwo2 = wts + 40*W55;
  unsigned short* wt_dfg  = wts + 43*W55;
  unsigned short* wt_dfp  = wts + 46*W55;
  unsigned short* wt_dhw1 = wts + 49*W55;

  float* out        = (float*)d_out;
  float* value_out  = out;
  float* logits_out = out + 8192;
  float* enc_out    = logits_out + (size_t)MM*16;
  float* d1_out     = enc_out + (size_t)BB*LL*HH*DH*DH;
  float* d2_out     = d1_out  + (size_t)BB*LL*HH*DH*DH;

  const size_t HS_L = (size_t)HH*DH*DH;

  {
    TP50 tp;
    const float* srcs[18] = {ewq, ewk, ewv, ewo, efg, efp, ehw1,
                             dwq1, dwk1, dwv1, dwo1, dwq2, dwk2, dwv2, dwo2, dfg, dfp, dhw1};
    const int cnt[18] = {3,3,3,3,3,3,1, 3,3,3,3,3,3,3,3,3,3,1};
    int z = 0;
    for (int i = 0; i < 18; ++i)
      for (int j = 0; j < cnt[i]; ++j){
        tp.s[z] = srcs[i] + (size_t)j*W55;
        tp.d[z] = wts + (size_t)z*W55;
        ++z;
      }
    wtpose_batch_kernel<<<dim3(16,16,50), dim3(32,8), 0, stream>>>(tp);
  }
  wtpose_kernel<<<dim3(4,16), dim3(32,8), 0, stream>>>(eow, wt_eow, OBSD, OBSD);
  wtpose_kernel<<<dim3(2,16), dim3(32,8), 0, stream>>>(daw, wt_daw, ACTD, 64);

  pe_kernel<<<(MM*EE)/256, 256, 0, stream>>>(stepc, peb);
  tsmax_kernel<<<BB, 256, 0, stream>>>(stepc, tmx);

  auto gemmF = [&](const unsigned short* A, const unsigned short* Wt, const float* bias,
                   float* C, int Kpad, float scale, int act){
    gemm_b_kernel<<<dim3(EE/64, MM/128), 256, 0, stream>>>(A, Wt, bias, C, nullptr, nullptr, Kpad, scale, act);
  };
  auto gemmB = [&](const unsigned short* A, const unsigned short* Wt,
                   unsigned short* Cb, int Kpad, float scale){
    gemm_b_kernel<<<dim3(EE/64, MM/128), 256, 0, stream>>>(A, Wt, nullptr, nullptr, Cb, nullptr, Kpad, scale, ACT_NONE);
  };
  auto gemmBT = [&](const unsigned short* A, const unsigned short* Wt,
                    unsigned short* Cb, unsigned short* CT, int Kpad, float scale){
    gemm_b_kernel<<<dim3(EE/64, MM/128), 256, 0, stream>>>(A, Wt, nullptr, nullptr, Cb, CT, Kpad, scale, ACT_NONE);
  };
  auto norm = [&](const float* af, const unsigned short* ab, const float* res,
                  const float* g, const float* p, const float* w,
                  unsigned short* o1, unsigned short* o2, int mode){
    norm_b_kernel<<<MM, 256, 0, stream>>>(af, ab, res, g, p, w, o1, o2, peb, mode);
  };
  auto retention = [&](const float* h0, unsigned short* o, int masked){
    retention_kernel<<<dim3(4, HH, BB), 256, 0, stream>>>(q_b, k_b, vT_b, h0, stepc, o, masked);
  };
  auto hstate = [&](const float* h0, float* o){
    hstate_partial_kernel<<<dim3(2,HH,BB), 256, 0, stream>>>(k_b, v_b, stepc, tmx, part);
    hstate_final_kernel<<<2048, 256, 0, stream>>>(part, h0, tmx, o);
  };

  // ---- encoder embed ----
  norm_obs_kernel<<<MM, 128, 0, stream>>>(obs, eoln, obs_n);
  gemmF(obs_n, wt_eow, nullptr, f32a, OBSD, 1.f, ACT_GELU);   // f32a = obs_rep

  // ---- encoder layers ----
  for (int i = 0; i < LL; ++i){
    if (i == 0) norm(f32a, nullptr, nullptr, nullptr, nullptr, eln, x_b, x_pe_b, NORM_PLAIN);
    else        norm(nullptr, xrep_b, nullptr, nullptr, nullptr, eln, x_b, x_pe_b, NORM_PLAIN);
    gemmB (x_pe_b, wt_ewq + i*W55, q_b, EE, 1.f);
    gemmB (x_pe_b, wt_ewk + i*W55, k_b, EE, INV_SQRT_D);
    gemmBT(x_pe_b, wt_ewv + i*W55, v_b, vT_b, EE, 1.f);
    retention(enc_hs + i*HS_L, t1_b, 0);
    hstate(enc_hs + i*HS_L, enc_out + i*HS_L);
    gemmF(t1_b, wt_ewo + i*W55, nullptr, f32a, EE, 1.f, ACT_NONE);
    norm(nullptr, x_b, f32a, nullptr, nullptr, eln1 + i*EE, t1_b, nullptr, NORM_ADD);
    gemmF(t1_b, wt_efg + i*W55, nullptr, f32a, EE, 1.f, ACT_NONE);
    gemmF(t1_b, wt_efp + i*W55, nullptr, f32b, EE, 1.f, ACT_NONE);
    norm(nullptr, t1_b, nullptr, f32a, f32b, eln2 + i*EE, xrep_b, xrep_pe_b, NORM_SWIGLU);
  }

  // ---- value head ----
  gemmF(xrep_b, wt_ehw1, ehb1, f32a, EE, 1.f, ACT_GELU);
  norm(f32a, nullptr, nullptr, nullptr, nullptr, ehln, t1_b, nullptr, NORM_PLAIN);
  value_head_kernel<<<MM/32, 256, 0, stream>>>(t1_b, ehw2, ehb2, value_out);

  // ---- decoder embed ----
  act_embed_kernel<<<(MM*64)/256, 256, 0, stream>>>(action, act_b);
  gemmF(act_b, wt_daw, nullptr, f32a, 64, 1.f, ACT_GELU);
  norm(f32a, nullptr, nullptr, nullptr, nullptr, dln, x_b, x_pe_b, NORM_PLAIN);

  // ---- decoder layers ----
  for (int i = 0; i < LL; ++i){
    gemmB (x_pe_b, wt_dwq1 + i*W55, q_b, EE, 1.f);
    gemmB (x_pe_b, wt_dwk1 + i*W55, k_b, EE, INV_SQRT_D);
    gemmBT(x_pe_b, wt_dwv1 + i*W55, v_b, vT_b, EE, 1.f);
    retention(dec_hs1 + i*HS_L, t1_b, 1);
    hstate(dec_hs1 + i*HS_L, d1_out + i*HS_L);
    gemmF(t1_b, wt_dwo1 + i*W55, nullptr, f32a, EE, 1.f, ACT_NONE);
    norm(nullptr, x_b, f32a, nullptr, nullptr, dln1 + i*EE, t1_b, t1_pe_b, NORM_ADD);   // r
    gemmB (xrep_pe_b, wt_dwq2 + i*W55, q_b, EE, 1.f);
    gemmB (t1_pe_b,   wt_dwk2 + i*W55, k_b, EE, INV_SQRT_D);
    gemmBT(t1_pe_b,   wt_dwv2 + i*W55, v_b, vT_b, EE, 1.f);
    retention(dec_hs2 + i*HS_L, t1_b, 1);
    hstate(dec_hs2 + i*HS_L, d2_out + i*HS_L);
    gemmF(t1_b, wt_dwo2 + i*W55, nullptr, f32a, EE, 1.f, ACT_NONE);
    norm(nullptr, xrep_b, f32a, nullptr, nullptr, dln2 + i*EE, x_b, nullptr, NORM_ADD); // y
    gemmF(x_b, wt_dfg + i*W55, nullptr, f32a, EE, 1.f, ACT_NONE);
    gemmF(x_b, wt_dfp + i*W55, nullptr, f32b, EE, 1.f, ACT_NONE);
    norm(nullptr, x_b, nullptr, f32a, f32b, dln3 + i*EE, x_b, x_pe_b, NORM_SWIGLU);
  }

  // ---- logits head ----
  gemmF(x_b, wt_dhw1, dhb1, f32a, EE, 1.f, ACT_GELU);
  norm(f32a, nullptr, nullptr, nullptr, nullptr, dhln, t1_b, nullptr, NORM_PLAIN);
  logits_head_kernel<<<MM/16, 256, 0, stream>>>(t1_b, dhw2, dhb2, logits_out);
}